// Round 1
// baseline (6977.695 us; speedup 1.0000x reference)
//
#include <hip/hip_runtime.h>
#include <stdint.h>

#define BB 8
#define NN 16384
#define SS 1024

typedef unsigned short u16;
static __device__ __forceinline__ float bf2f(u16 u){
    union { uint32_t u; float f; } v; v.u = ((uint32_t)u) << 16; return v.f;
}
static __device__ __forceinline__ u16 f2bf(float f){
    union { float f; uint32_t u; } v; v.f = f;
    return (u16)((v.u + 0x7FFFu + ((v.u >> 16) & 1u)) >> 16);
}

// ---------------- FPS: G blocks per batch, spin-synced via agent-scope atomics ----------
// Previous single-block version: 2297us, Occupancy 0.77% (8 CUs busy), VALUBusy 1.9%,
// VGPR=84 (spilled 128 floats/thread). Split each batch over FPS_G=4 blocks:
// 8 pts/thread -> no spill; per-iter cross-block argmax exchange through one u64
// agent-scope slot per (block, parity). Packed u64 = valbits<<32 | tag<<14 | (16383-n):
// unsigned max == (value, lowest-n) argmax since distances >= 0 and tags are equal.
// Tag check (it+1, parity-double-buffered) makes it graph-replay safe; init kernel
// zeroes slots so first-launch garbage can't alias tag.
#define FPS_G 4

__global__ void fps_init_kernel(unsigned long long* __restrict__ slots){
    int t = threadIdx.x;
    if (t < BB*FPS_G*2) slots[t] = 0ull;
}

__global__ __launch_bounds__(512) void fps_kernel(const float* __restrict__ xyz,
                                                  int* __restrict__ fps_idx,
                                                  unsigned long long* __restrict__ slots){
#pragma clang fp contract(off)
    int bg = blockIdx.x;
    int b = bg >> 2, g = bg & (FPS_G-1);
    int t = threadIdx.x;
    const float* xb = xyz + (size_t)b*3*NN;
    const int PPT = NN/FPS_G/512;   // 8 points per thread
    int nbase = g*(NN/FPS_G) + t;
    float px[PPT], py[PPT], pz[PPT], dd[PPT];
#pragma unroll
    for (int j=0;j<PPT;++j){
        int n = nbase + j*512;
        px[j] = xb[n];
        py[j] = xb[NN+n];
        pz[j] = xb[2*NN+n];
        dd[j] = 1e10f;
    }
    __shared__ float rv[2][8];
    __shared__ int   rn[2][8];
    int lane = t & 63, wid = t >> 6;
    int far = 0;
    int* outp = fps_idx + b*SS;
    unsigned long long* sb = slots + b*(FPS_G*2);
    float cx = xb[0], cy = xb[NN], cz = xb[2*NN];
    for (int it=0; it<SS; ++it){
        if (g==0 && t==0) outp[it] = far;
        float bestv = -1.0f; int bestn = 0x7fffffff;
#pragma unroll
        for (int j=0;j<PPT;++j){
            float dx = px[j]-cx, dy = py[j]-cy, dz = pz[j]-cz;
            float d = dx*dx + dy*dy;
            d = d + dz*dz;
            float dm = dd[j] < d ? dd[j] : d;   // np.minimum, exact
            dd[j] = dm;
            if (dm > bestv){ bestv = dm; bestn = nbase + j*512; }  // strict > keeps lowest n in-thread
        }
        // intra-wave argmax (exact (value, lowest-n) order)
#pragma unroll
        for (int off=32; off>0; off>>=1){
            float ov = __shfl_down(bestv, off);
            int   on = __shfl_down(bestn, off);
            if (ov > bestv || (ov == bestv && on < bestn)){ bestv = ov; bestn = on; }
        }
        int pb = it & 1;
        if (lane == 0){ rv[pb][wid] = bestv; rn[pb][wid] = bestn; }
        __syncthreads();
        // every wave reduces the 8 wave-results identically (no 2nd barrier needed)
        float v2 = (lane < 8) ? rv[pb][lane] : -1.0f;
        int   n2 = (lane < 8) ? rn[pb][lane] : 0x7fffffff;
#pragma unroll
        for (int off=4; off>0; off>>=1){
            float ov = __shfl_down(v2, off);
            int   on = __shfl_down(n2, off);
            if (ov > v2 || (ov == v2 && on < n2)){ v2 = ov; n2 = on; }
        }
        float bv = __shfl(v2, 0);
        int   bn = __shfl(n2, 0);
        unsigned int tag = (unsigned int)(it + 1);   // 1..1024, fits 11 bits
        unsigned long long packed = ((unsigned long long)__float_as_uint(bv) << 32)
                                  | ((unsigned long long)tag << 14)
                                  | (unsigned long long)(unsigned int)(16383 - bn);
        if (wid == 0 && lane == 0)
            __hip_atomic_store(&sb[g*2 + pb], packed, __ATOMIC_RELEASE, __HIP_MEMORY_SCOPE_AGENT);
        // every wave polls all FPS_G slots (lanes 0..3), then combines
        unsigned long long pk = packed;
        if (lane < FPS_G){
            unsigned long long* sp = &sb[lane*2 + pb];
            do {
                pk = __hip_atomic_load(sp, __ATOMIC_ACQUIRE, __HIP_MEMORY_SCOPE_AGENT);
            } while ((((unsigned int)(pk >> 14)) & 0x7FFu) != tag);
        }
#pragma unroll
        for (int off=1; off<FPS_G; off<<=1){
            unsigned long long o = __shfl_xor(pk, off);
            pk = (o > pk) ? o : pk;     // u64 max == (value, lowest-n) argmax
        }
        pk = __shfl(pk, 0);
        far = 16383 - (int)(pk & 0x3FFFull);
        cx = xb[far]; cy = xb[NN+far]; cz = xb[2*NN+far];
    }
}

// ---------------- gather query coords + write new_xyz output (fp32) ----------------
__global__ void gather_q_kernel(const float* __restrict__ xyz, const int* __restrict__ fps_idx,
                                float* __restrict__ q, float* __restrict__ out_xyz){
    int i = blockIdx.x*blockDim.x + threadIdx.x;
    if (i >= BB*SS) return;
    int b = i >> 10, s = i & 1023;
    int idx = fps_idx[i];
    for (int c=0;c<3;++c){
        float v = xyz[((size_t)b*3+c)*NN + idx];
        q[i*3+c] = v;
        out_xyz[((size_t)b*3+c)*SS + s] = v;
    }
}

// ---------------- build ptsT[b][n][64] ----------------
__global__ __launch_bounds__(256) void build_ptsT_kernel(const float* __restrict__ xyz, const float* __restrict__ pts,
                                                         float* __restrict__ ptsT){
    __shared__ float tile[64][65];
    int b = blockIdx.y;
    int n0 = blockIdx.x * 64;
    int t = threadIdx.x;
    int ln = t & 63, cr = t >> 6;
    for (int c = cr; c < 64; c += 4){
        float v;
        if (c < 3) v = xyz[((size_t)b*3 + c)*NN + n0 + ln];
        else       v = pts[((size_t)b*61 + (c-3))*NN + n0 + ln];
        tile[ln][c] = v;
    }
    __syncthreads();
    int lc = t & 63, nr = t >> 6;
    for (int n = nr; n < 64; n += 4){
        ptsT[((size_t)b*NN + n0 + n)*64 + lc] = tile[n][lc];
    }
}

// ---------------- ball query ----------------
__global__ __launch_bounds__(256) void ballquery_kernel(const float* __restrict__ xyz, const float* __restrict__ q,
        int* __restrict__ idx0, int* __restrict__ idx1, int* __restrict__ idx2,
        float r2a, float r2b, float r2c){
#pragma clang fp contract(off)
    __shared__ int lds[4][112];
    int t = threadIdx.x;
    int w = t >> 6, lane = t & 63;
    int qi = blockIdx.x*4 + w;
    int b = qi >> 10;
    const float* xb = xyz + (size_t)b*3*NN;
    float qx = q[qi*3], qy = q[qi*3+1], qz = q[qi*3+2];
    float qn = qx*qx + qy*qy; qn = qn + qz*qz;
    int* l0 = lds[w];
    int* l1 = l0 + 16;
    int* l2 = l0 + 48;
    l0[lane] = 0;
    if (lane < 48) l0[64+lane] = 0;
    int c0=0, c1=0, c2=0;
    uint64_t below = (1ull << lane) - 1ull;
    for (int ch=0; ch<256; ++ch){
        int n = ch*64 + lane;
        float x = xb[n], y = xb[NN+n], z = xb[2*NN+n];
        float dn = x*x + y*y; dn = dn + z*z;
        float dot = qx*x + qy*y; dot = dot + qz*z;
        float d = -2.0f*dot + qn;
        d = d + dn;
        bool o0 = d <= r2a, o1 = d <= r2b, o2 = d <= r2c;
        uint64_t m0 = __ballot(o0), m1 = __ballot(o1), m2 = __ballot(o2);
        if (c0 < 16){
            int p = c0 + (int)__popcll(m0 & below);
            if (o0 && p < 16) l0[p] = n;
            c0 += (int)__popcll(m0); if (c0 > 16) c0 = 16;
        }
        if (c1 < 32){
            int p = c1 + (int)__popcll(m1 & below);
            if (o1 && p < 32) l1[p] = n;
            c1 += (int)__popcll(m1); if (c1 > 32) c1 = 32;
        }
        if (c2 < 64){
            int p = c2 + (int)__popcll(m2 & below);
            if (o2 && p < 64) l2[p] = n;
            c2 += (int)__popcll(m2); if (c2 > 64) c2 = 64;
        }
        if (c0>=16 && c1>=32 && c2>=64) break;
    }
    __syncthreads();
    int f0 = l0[0], f1 = l1[0], f2 = l2[0];
    if (lane >= c0 && lane < 16) l0[lane] = f0;
    if (lane >= c1 && lane < 32) l1[lane] = f1;
    if (lane >= c2)              l2[lane] = f2;
    __syncthreads();
    if (lane < 16) idx0[(size_t)qi*16 + lane] = l0[lane];
    if (lane < 32) idx1[(size_t)qi*32 + lane] = l1[lane];
    idx2[(size_t)qi*64 + lane] = l2[lane];
}

// ---------------- MAC helper ----------------
template<int UU>
__device__ __forceinline__ void fma_tile(float (&acc)[4][UU][4], float4 a4, const float* bsrow, int jbase){
#pragma unroll
    for (int uu=0; uu<UU; ++uu){
        float4 b4 = *(const float4*)(bsrow + jbase + 64*uu);
        acc[0][uu][0]+=a4.x*b4.x; acc[0][uu][1]+=a4.x*b4.y; acc[0][uu][2]+=a4.x*b4.z; acc[0][uu][3]+=a4.x*b4.w;
        acc[1][uu][0]+=a4.y*b4.x; acc[1][uu][1]+=a4.y*b4.y; acc[1][uu][2]+=a4.y*b4.z; acc[1][uu][3]+=a4.y*b4.w;
        acc[2][uu][0]+=a4.z*b4.x; acc[2][uu][1]+=a4.z*b4.y; acc[2][uu][2]+=a4.z*b4.z; acc[2][uu][3]+=a4.z*b4.w;
        acc[3][uu][0]+=a4.w*b4.x; acc[3][uu][1]+=a4.w*b4.y; acc[3][uu][2]+=a4.w*b4.z; acc[3][uu][3]+=a4.w*b4.w;
    }
}

// ---------------- unified GEMM: As [k][row] x W[OO][CC] staged in k-slabs -> acc ----------------
template<int CC, int OO>
__device__ __forceinline__ void gemm_slab(const float* __restrict__ W, int t, int i, int j,
                                          float* As, float* Bs, float (&acc)[4][OO/64][4]){
    constexpr int KS = (4096/OO) < 32 ? (4096/OO) : 32;
    constexpr int QQ = KS/4;
    constexpr int NSLOT = KS*OO/4;
    for (int k0=0; k0<CC; k0+=KS){
        __syncthreads();
#pragma unroll
        for (int it=0; it<NSLOT/256; ++it){
            int slot = t + it*256;
            int o = slot / QQ, qq = slot % QQ;
            float4 wv = *(const float4*)(W + o*CC + k0 + qq*4);
            Bs[(qq*4+0)*OO + o] = wv.x; Bs[(qq*4+1)*OO + o] = wv.y;
            Bs[(qq*4+2)*OO + o] = wv.z; Bs[(qq*4+3)*OO + o] = wv.w;
        }
        __syncthreads();
#pragma unroll 4
        for (int kk=0; kk<KS; ++kk){
            float4 a4 = *(const float4*)&As[(k0+kk)*64 + i*4];
            fma_tile<OO/64>(acc, a4, &Bs[kk*OO], j*4);
        }
    }
    __syncthreads();
}

template<int UU>
__device__ __forceinline__ void bias_add(float (&acc)[4][UU][4], const float* __restrict__ bsrc, int j){
#pragma unroll
    for (int uu=0; uu<UU; ++uu)
#pragma unroll
    for (int e=0; e<4; ++e){
        float bb = bsrc[j*4 + 64*uu + e];
#pragma unroll
        for (int rr=0; rr<4; ++rr) acc[rr][uu][e] += bb;
    }
}

template<int UU>
__device__ __forceinline__ void act_to_As(float (&acc)[4][UU][4], const float* __restrict__ bsrc,
                                          const float* __restrict__ sc, const float* __restrict__ sh,
                                          int i, int j, float* As){
#pragma unroll
    for (int uu=0; uu<UU; ++uu)
#pragma unroll
    for (int e=0; e<4; ++e){
        int c = j*4 + 64*uu + e;
        float bb = bsrc[c], scv = sc[c], shv = sh[c];
#pragma unroll
        for (int rr=0; rr<4; ++rr)
            As[c*64 + i*4+rr] = fmaxf(0.f, (acc[rr][uu][e]+bb)*scv + shv);
    }
}

template<int UU>
__device__ __forceinline__ void zstore(float (&acc)[4][UU][4], u16* __restrict__ zbuf, int m0, int i, int j){
    constexpr int OO = UU*64;
#pragma unroll
    for (int rr=0; rr<4; ++rr){
        size_t row = (size_t)(m0 + i*4 + rr);
#pragma unroll
        for (int uu=0; uu<UU; ++uu){
            ushort4 o4;
            o4.x = f2bf(acc[rr][uu][0]); o4.y = f2bf(acc[rr][uu][1]);
            o4.z = f2bf(acc[rr][uu][2]); o4.w = f2bf(acc[rr][uu][3]);
            *(ushort4*)&zbuf[row*OO + j*4 + 64*uu] = o4;
        }
    }
}

template<int OO>
__device__ __forceinline__ void zload_to_As(const u16* __restrict__ zbuf, int m0,
                                            const float* __restrict__ sc, const float* __restrict__ sh,
                                            int t, float* As){
    constexpr int CQ = OO/4;
    constexpr int ITZ = 64*CQ/256;
#pragma unroll
    for (int it=0; it<ITZ; ++it){
        int slot = t + it*256;
        int r = slot / CQ, cq = slot % CQ;
        ushort4 zv = *(const ushort4*)&zbuf[((size_t)(m0+r))*OO + cq*4];
        int c = cq*4;
        As[(c+0)*64+r] = fmaxf(0.f, bf2f(zv.x)*sc[c+0] + sh[c+0]);
        As[(c+1)*64+r] = fmaxf(0.f, bf2f(zv.y)*sc[c+1] + sh[c+1]);
        As[(c+2)*64+r] = fmaxf(0.f, bf2f(zv.z)*sc[c+2] + sh[c+2]);
        As[(c+3)*64+r] = fmaxf(0.f, bf2f(zv.w)*sc[c+3] + sh[c+3]);
    }
}

// ---------------- stats / extrema epilogue ----------------
template<int UU, int K, bool EXT>
__device__ __forceinline__ void stats_write(float (&z)[4][UU][4], int t, int m0, int blk,
    float* scr, float* __restrict__ pS, float* __restrict__ pQ,
    float* __restrict__ gmax, float* __restrict__ gmin)
{
    constexpr int O = UU*64;
    int j = t & 15;
    float s1[UU][4], s2[UU][4], mx[UU][4], mn[UU][4];
#pragma unroll
    for (int uu=0; uu<UU; ++uu)
#pragma unroll
    for (int e=0; e<4; ++e){
        float v0=z[0][uu][e], v1=z[1][uu][e], v2=z[2][uu][e], v3=z[3][uu][e];
        s1[uu][e]=(v0+v1)+(v2+v3);
        s2[uu][e]=(v0*v0+v1*v1)+(v2*v2+v3*v3);
        if (EXT){
            mx[uu][e]=fmaxf(fmaxf(v0,v1),fmaxf(v2,v3));
            mn[uu][e]=fminf(fminf(v0,v1),fminf(v2,v3));
        }
    }
#pragma unroll
    for (int uu=0; uu<UU; ++uu)
#pragma unroll
    for (int e=0; e<4; ++e){
        s1[uu][e] += __shfl_xor(s1[uu][e],16); s1[uu][e] += __shfl_xor(s1[uu][e],32);
        s2[uu][e] += __shfl_xor(s2[uu][e],16); s2[uu][e] += __shfl_xor(s2[uu][e],32);
        if (EXT){
            mx[uu][e] = fmaxf(mx[uu][e], __shfl_xor(mx[uu][e],16)); mx[uu][e] = fmaxf(mx[uu][e], __shfl_xor(mx[uu][e],32));
            mn[uu][e] = fminf(mn[uu][e], __shfl_xor(mn[uu][e],16)); mn[uu][e] = fminf(mn[uu][e], __shfl_xor(mn[uu][e],32));
        }
    }
    int wv = t >> 6;
    if ((t & 63) < 16){
#pragma unroll
        for (int uu=0; uu<UU; ++uu)
#pragma unroll
        for (int e=0; e<4; ++e){
            int c = j*4 + 64*uu + e;
            scr[0*4*O + wv*O + c] = s1[uu][e];
            scr[1*4*O + wv*O + c] = s2[uu][e];
            if (EXT){
                scr[2*4*O + wv*O + c] = mx[uu][e];
                scr[3*4*O + wv*O + c] = mn[uu][e];
            }
        }
    }
    __syncthreads();
    for (int c=t; c<O; c+=256){
        float S = ((scr[c] + scr[O+c]) + (scr[2*O+c] + scr[3*O+c]));
        float Q = ((scr[4*O+c] + scr[5*O+c]) + (scr[6*O+c] + scr[7*O+c]));
        pS[(size_t)blk*O + c] = S;
        pQ[(size_t)blk*O + c] = Q;
        if (EXT){
            constexpr int G  = 64/K;
            constexpr int WG = K/16;
#pragma unroll
            for (int g=0; g<G; ++g){
                float M1 = scr[2*4*O + (g*WG)*O + c];
                float M2 = scr[3*4*O + (g*WG)*O + c];
#pragma unroll
                for (int ww=1; ww<WG; ++ww){
                    M1 = fmaxf(M1, scr[2*4*O + (g*WG+ww)*O + c]);
                    M2 = fminf(M2, scr[3*4*O + (g*WG+ww)*O + c]);
                }
                int bs = m0/K + g;
                gmax[(size_t)bs*O + c] = M1;
                gmin[(size_t)bs*O + c] = M2;
            }
        }
    }
}

template<int K>
__device__ __forceinline__ void gather_A0(const float* __restrict__ ptsT, const float* __restrict__ q,
                                          const int* __restrict__ gidx, int m0, int t, float* As){
    int r = t >> 2, q4 = t & 3;
    int m = m0 + r;
    int idx = gidx[m];
    int bs = m / K;
    int b = bs >> 10;
    const float* base = ptsT + ((size_t)b*NN + idx)*64;
    float qx=0.f, qy=0.f, qz=0.f;
    if (q4 == 0){ qx = q[bs*3]; qy = q[bs*3+1]; qz = q[bs*3+2]; }
#pragma unroll
    for (int ii=0; ii<4; ++ii){
        int c0 = q4*16 + ii*4;
        float4 v = *(const float4*)(base + c0);
        if (q4==0 && ii==0){ v.x -= qx; v.y -= qy; v.z -= qz; }
        As[(c0+0)*64 + r] = v.x; As[(c0+1)*64 + r] = v.y;
        As[(c0+2)*64 + r] = v.z; As[(c0+3)*64 + r] = v.w;
    }
}

// ---------------- fused MLP phases ----------------
template<int PHASE, int K, int O1, int O2, int O3>
__global__ __launch_bounds__(256) void fused_mlp(
    const float* __restrict__ ptsT, const float* __restrict__ q, const int* __restrict__ gidx,
    const float* __restrict__ W1, const float* __restrict__ b1,
    const float* __restrict__ W2, const float* __restrict__ b2,
    const float* __restrict__ W3, const float* __restrict__ b3,
    const float* __restrict__ sc1, const float* __restrict__ sh1,
    const float* __restrict__ sc2, const float* __restrict__ sh2,
    float* __restrict__ pS, float* __restrict__ pQ,
    float* __restrict__ gmax, float* __restrict__ gmin,
    u16* __restrict__ zbuf)
{
    __shared__ float As[8192];   // 32 KB
    __shared__ float Bs[4096];   // 16 KB
    int t = threadIdx.x;
    int m0 = blockIdx.x * 64;
    int j = t & 15, i = t >> 4;

    if constexpr (PHASE == 1){
        gather_A0<K>(ptsT, q, gidx, m0, t, As);
        float acc1[4][O1/64][4] = {};
        gemm_slab<64,O1>(W1, t, i, j, As, Bs, acc1);
        bias_add<O1/64>(acc1, b1, j);
        if (zbuf) zstore<O1/64>(acc1, zbuf, m0, i, j);
        stats_write<O1/64,K,false>(acc1, t, m0, blockIdx.x, Bs, pS, pQ, gmax, gmin);
        return;
    }

    if constexpr (PHASE == 2){
        if (zbuf){
            zload_to_As<O1>(zbuf, m0, sc1, sh1, t, As);
        } else {
            gather_A0<K>(ptsT, q, gidx, m0, t, As);
            float acc1[4][O1/64][4] = {};
            gemm_slab<64,O1>(W1, t, i, j, As, Bs, acc1);
            act_to_As<O1/64>(acc1, b1, sc1, sh1, i, j, As);
        }
        float acc2[4][O2/64][4] = {};
        gemm_slab<O1,O2>(W2, t, i, j, As, Bs, acc2);
        bias_add<O2/64>(acc2, b2, j);
        if (zbuf) zstore<O2/64>(acc2, zbuf, m0, i, j);   // overwrites z1 rows (block-local, safe)
        stats_write<O2/64,K,false>(acc2, t, m0, blockIdx.x, Bs, pS, pQ, gmax, gmin);
        return;
    }

    if constexpr (PHASE == 3){
        gather_A0<K>(ptsT, q, gidx, m0, t, As);
        float acc1[4][O1/64][4] = {};
        gemm_slab<64,O1>(W1, t, i, j, As, Bs, acc1);
        act_to_As<O1/64>(acc1, b1, sc1, sh1, i, j, As);
        float acc2[4][O2/64][4] = {};
        gemm_slab<O1,O2>(W2, t, i, j, As, Bs, acc2);
        act_to_As<O2/64>(acc2, b2, sc2, sh2, i, j, As);
    } else {
        // PHASE 4
        zload_to_As<O2>(zbuf, m0, sc2, sh2, t, As);
    }

    float acc3[4][O3/64][4] = {};
    gemm_slab<O2,O3>(W3, t, i, j, As, Bs, acc3);
    bias_add<O3/64>(acc3, b3, j);
    stats_write<O3/64,K,true>(acc3, t, m0, blockIdx.x, Bs, pS, pQ, gmax, gmin);
}

// ---------------- finalize BN stats (fp64 accumulation) ----------------
__global__ __launch_bounds__(256) void finalize_d_kernel(const float* __restrict__ pS, const float* __restrict__ pQ,
                                      const float* __restrict__ g, const float* __restrict__ bt,
                                      float* __restrict__ sc, float* __restrict__ sh, int nb, double invM){
    __shared__ double red[512];
    int c = blockIdx.x;
    int O = gridDim.x;
    int t = threadIdx.x;
    double S=0.0, Q=0.0;
    for (int v=t; v<nb; v+=256){ S += (double)pS[(size_t)v*O + c]; Q += (double)pQ[(size_t)v*O + c]; }
    red[t]=S; red[256+t]=Q;
    __syncthreads();
    for (int s=128; s>0; s>>=1){
        if (t<s){ red[t]+=red[t+s]; red[256+t]+=red[256+t+s]; }
        __syncthreads();
    }
    if (t==0){
        double mean = red[0]*invM;
        double var  = red[256]*invM - mean*mean;
        double scale = (double)g[c] / sqrt(var + 1e-5);
        sc[c] = (float)scale;
        sh[c] = (float)((double)bt[c] - mean*scale);
    }
}

// ---------------- BN+relu on pooled extrema -> output (fp32) ----------------
__global__ void final_out_kernel(const float* __restrict__ gmax, const float* __restrict__ gmin,
                                 const float* __restrict__ sc, const float* __restrict__ sh,
                                 float* __restrict__ outp, int O, int logO, int chbase){
    int gid = blockIdx.x*256 + threadIdx.x;
    int c  = gid & (O-1);
    int bs = gid >> logO;
    int b = bs >> 10, s = bs & 1023;
    float scale = sc[c];
    float v = (scale >= 0.f) ? gmax[gid] : gmin[gid];
    float r = fmaxf(0.f, scale*v + sh[c]);
    outp[((size_t)(b*640 + chbase + c))*SS + s] = r;
}

__global__ void ws_marker_kernel(float* outp, float wsval){ if (threadIdx.x==0) outp[0] = wsval; }

template<int K, int O1, int O2, int O3>
static void run_branch(const float* ptsT, const float* q, const int* gidx,
                       float* pS, float* pQ, float* gmax, float* gmin,
                       float* sc1, float* sh1, float* sc2, float* sh2, float* sc3, float* sh3,
                       u16* z2buf, bool use_z,
                       void* const* d_in, int wbase, float* np_out, int chbase, hipStream_t stream)
{
    const int M = BB*SS*K;
    const int nb = M/64;
    auto wp = [&](int jl, int which)->const float* { return (const float*)d_in[2 + (wbase+jl)*4 + which]; };
    const double invM = 1.0 / (double)M;
    u16* zb = use_z ? z2buf : (u16*)nullptr;

    fused_mlp<1,K,O1,O2,O3><<<nb,256,0,stream>>>(ptsT,q,gidx,
        wp(0,0),wp(0,1), wp(1,0),wp(1,1), wp(2,0),wp(2,1),
        sc1,sh1, sc2,sh2, pS,pQ, gmax,gmin, zb);
    finalize_d_kernel<<<O1,256,0,stream>>>(pS,pQ, wp(0,2), wp(0,3), sc1, sh1, nb, invM);

    fused_mlp<2,K,O1,O2,O3><<<nb,256,0,stream>>>(ptsT,q,gidx,
        wp(0,0),wp(0,1), wp(1,0),wp(1,1), wp(2,0),wp(2,1),
        sc1,sh1, sc2,sh2, pS,pQ, gmax,gmin, zb);
    finalize_d_kernel<<<O2,256,0,stream>>>(pS,pQ, wp(1,2), wp(1,3), sc2, sh2, nb, invM);

    if (use_z){
        fused_mlp<4,K,O1,O2,O3><<<nb,256,0,stream>>>(ptsT,q,gidx,
            wp(0,0),wp(0,1), wp(1,0),wp(1,1), wp(2,0),wp(2,1),
            sc1,sh1, sc2,sh2, pS,pQ, gmax,gmin, z2buf);
    } else {
        fused_mlp<3,K,O1,O2,O3><<<nb,256,0,stream>>>(ptsT,q,gidx,
            wp(0,0),wp(0,1), wp(1,0),wp(1,1), wp(2,0),wp(2,1),
            sc1,sh1, sc2,sh2, pS,pQ, gmax,gmin, nullptr);
    }
    finalize_d_kernel<<<O3,256,0,stream>>>(pS,pQ, wp(2,2), wp(2,3), sc3, sh3, nb, invM);

    final_out_kernel<<<(BB*SS*O3)/256,256,0,stream>>>(gmax,gmin, sc3,sh3, np_out, O3, (O3==256?8:7), chbase);
}

extern "C" void kernel_launch(void* const* d_in, const int* in_sizes, int n_in,
                              void* d_out, int out_size, void* d_ws, size_t ws_size,
                              hipStream_t stream)
{
    const float* xyz = (const float*)d_in[0];
    const float* pts = (const float*)d_in[1];
    float* outp = (float*)d_out;

    char* wsb = (char*)d_ws;
    size_t off = 0;
    auto alloc = [&](size_t bytes) -> void* {
        off = (off + 255) & ~(size_t)255;
        void* p = wsb + off;
        off += bytes;
        return p;
    };
    int*   fps_idx = (int*)  alloc((size_t)BB*SS*4);
    float* q       = (float*)alloc((size_t)BB*SS*3*4);
    int*   idx0    = (int*)  alloc((size_t)BB*SS*16*4);
    int*   idx1    = (int*)  alloc((size_t)BB*SS*32*4);
    int*   idx2    = (int*)  alloc((size_t)BB*SS*64*4);
    float* ptsT    = (float*)alloc((size_t)BB*NN*64*4);
    float* pS      = (float*)alloc((size_t)8192*256*4);
    float* pQ      = (float*)alloc((size_t)8192*256*4);
    float* gmax    = (float*)alloc((size_t)8192*256*4);
    float* gmin    = (float*)alloc((size_t)8192*256*4);
    float* sc1     = (float*)alloc(256*4);
    float* sh1     = (float*)alloc(256*4);
    float* sc2     = (float*)alloc(256*4);
    float* sh2     = (float*)alloc(256*4);
    float* sc3     = (float*)alloc(256*4);
    float* sh3     = (float*)alloc(256*4);
    unsigned long long* fps_slots = (unsigned long long*)alloc((size_t)BB*FPS_G*2*8);

    if (off > ws_size){
        ws_marker_kernel<<<1,64,0,stream>>>(outp, (float)ws_size);
        return;
    }

    u16* z2buf = (u16*)alloc((size_t)BB*SS*64*128*2);
    bool use_z = (off <= ws_size);

    build_ptsT_kernel<<<dim3(NN/64, BB), 256, 0, stream>>>(xyz, pts, ptsT);
    fps_init_kernel<<<1, 64, 0, stream>>>(fps_slots);
    fps_kernel<<<BB*FPS_G, 512, 0, stream>>>(xyz, fps_idx, fps_slots);
    gather_q_kernel<<<32, 256, 0, stream>>>(xyz, fps_idx, q, outp);

    const float r2a = (float)(0.1*0.1);
    const float r2b = (float)(0.2*0.2);
    const float r2c = (float)(0.4*0.4);
    ballquery_kernel<<<2048, 256, 0, stream>>>(xyz, q, idx0, idx1, idx2, r2a, r2b, r2c);

    float* np_out = outp + (size_t)BB*3*SS;
    run_branch<16, 64, 64,128>(ptsT, q, idx0, pS,pQ, gmax,gmin, sc1,sh1,sc2,sh2,sc3,sh3, z2buf, use_z, d_in, 0, np_out,   0, stream);
    run_branch<32,128,128,256>(ptsT, q, idx1, pS,pQ, gmax,gmin, sc1,sh1,sc2,sh2,sc3,sh3, z2buf, use_z, d_in, 3, np_out, 128, stream);
    run_branch<64,128,128,256>(ptsT, q, idx2, pS,pQ, gmax,gmin, sc1,sh1,sc2,sh2,sc3,sh3, z2buf, use_z, d_in, 6, np_out, 384, stream);

    hipError_t e = hipGetLastError();
    if (e != hipSuccess){
        ws_marker_kernel<<<1,64,0,stream>>>(outp, 1000.0f + (float)(int)e);
    }
}

// Round 2
// 4577.793 us; speedup vs baseline: 1.5242x; 1.5242x over previous
//
#include <hip/hip_runtime.h>
#include <stdint.h>

#define BB 8
#define NN 16384
#define SS 1024

typedef unsigned short u16;
static __device__ __forceinline__ float bf2f(u16 u){
    union { uint32_t u; float f; } v; v.u = ((uint32_t)u) << 16; return v.f;
}
static __device__ __forceinline__ u16 f2bf(float f){
    union { float f; uint32_t u; } v; v.f = f;
    return (u16)((v.u + 0x7FFFu + ((v.u >> 16) & 1u)) >> 16);
}

// ---------------- FPS: one block per batch, 1024 thr, 16 pts/thread ----------------
// History: 512thr x 32pts spilled (VGPR=84, 2297us). 4-block split + agent-scope
// atomic exchange regressed to 4808us (cross-XCD store->poll on serial path, AND
// dropped asm-redefinition let compiler re-load px/py/pz every iter: VGPR=32,
// FETCH 10x). This version: 1024 thr x 16 pts = 64 array floats + temps < 128 VGPR
// cap (launch_bounds 1024 -> 4 waves/SIMD), no spill, no cross-block sync.
// asm redefinition is LOAD-BEARING: prevents rematerialization of the coord loads.
__global__ __launch_bounds__(1024) void fps_kernel(const float* __restrict__ xyz,
                                                   int* __restrict__ fps_idx){
#pragma clang fp contract(off)
    int b = blockIdx.x;
    int t = threadIdx.x;
    const float* xb = xyz + (size_t)b*3*NN;
    float px[16], py[16], pz[16], dd[16];
#pragma unroll
    for (int j=0;j<16;++j){
        int n = t + j*1024;
        px[j] = xb[n];
        py[j] = xb[NN+n];
        pz[j] = xb[2*NN+n];
        dd[j] = 1e10f;
    }
    // opaque redefinition: compiler cannot rematerialize the loads
#pragma unroll
    for (int j=0;j<16;++j){
        asm volatile("" : "+v"(px[j]), "+v"(py[j]), "+v"(pz[j]));
    }
    __shared__ float rv[2][16];
    __shared__ int   rn[2][16];
    int lane = t & 63, wid = t >> 6;
    int far = 0;
    int* outp = fps_idx + b*SS;
    float cx = xb[0], cy = xb[NN], cz = xb[2*NN];
    for (int it=0; it<SS; ++it){
        if (t==0) outp[it] = far;
        float bestv = -1.0f; int bestn = 0x7fffffff;
#pragma unroll
        for (int j=0;j<16;++j){
            float dx = px[j]-cx, dy = py[j]-cy, dz = pz[j]-cz;
            float d = dx*dx + dy*dy;
            d = d + dz*dz;
            float dm = dd[j] < d ? dd[j] : d;   // np.minimum, exact
            dd[j] = dm;
            if (dm > bestv){ bestv = dm; bestn = t + j*1024; }  // strict > keeps lowest n in-thread
        }
        // intra-wave argmax, exact (value, lowest-n) order
#pragma unroll
        for (int off=32; off>0; off>>=1){
            float ov = __shfl_down(bestv, off);
            int   on = __shfl_down(bestn, off);
            if (ov > bestv || (ov == bestv && on < bestn)){ bestv = ov; bestn = on; }
        }
        int pb = it & 1;
        if (lane == 0){ rv[pb][wid] = bestv; rn[pb][wid] = bestn; }
        __syncthreads();
        // every wave reduces the 16 wave-results identically (parity dbuf -> no 2nd barrier)
        float v2 = (lane < 16) ? rv[pb][lane] : -1.0f;
        int   n2 = (lane < 16) ? rn[pb][lane] : 0x7fffffff;
#pragma unroll
        for (int off=8; off>0; off>>=1){
            float ov = __shfl_down(v2, off);
            int   on = __shfl_down(n2, off);
            if (ov > v2 || (ov == v2 && on < n2)){ v2 = ov; n2 = on; }
        }
        far = __shfl(n2, 0);
        cx = xb[far]; cy = xb[NN+far]; cz = xb[2*NN+far];
    }
}

// ---------------- gather query coords + write new_xyz output (fp32) ----------------
__global__ void gather_q_kernel(const float* __restrict__ xyz, const int* __restrict__ fps_idx,
                                float* __restrict__ q, float* __restrict__ out_xyz){
    int i = blockIdx.x*blockDim.x + threadIdx.x;
    if (i >= BB*SS) return;
    int b = i >> 10, s = i & 1023;
    int idx = fps_idx[i];
    for (int c=0;c<3;++c){
        float v = xyz[((size_t)b*3+c)*NN + idx];
        q[i*3+c] = v;
        out_xyz[((size_t)b*3+c)*SS + s] = v;
    }
}

// ---------------- build ptsT[b][n][64] ----------------
__global__ __launch_bounds__(256) void build_ptsT_kernel(const float* __restrict__ xyz, const float* __restrict__ pts,
                                                         float* __restrict__ ptsT){
    __shared__ float tile[64][65];
    int b = blockIdx.y;
    int n0 = blockIdx.x * 64;
    int t = threadIdx.x;
    int ln = t & 63, cr = t >> 6;
    for (int c = cr; c < 64; c += 4){
        float v;
        if (c < 3) v = xyz[((size_t)b*3 + c)*NN + n0 + ln];
        else       v = pts[((size_t)b*61 + (c-3))*NN + n0 + ln];
        tile[ln][c] = v;
    }
    __syncthreads();
    int lc = t & 63, nr = t >> 6;
    for (int n = nr; n < 64; n += 4){
        ptsT[((size_t)b*NN + n0 + n)*64 + lc] = tile[n][lc];
    }
}

// ---------------- ball query ----------------
__global__ __launch_bounds__(256) void ballquery_kernel(const float* __restrict__ xyz, const float* __restrict__ q,
        int* __restrict__ idx0, int* __restrict__ idx1, int* __restrict__ idx2,
        float r2a, float r2b, float r2c){
#pragma clang fp contract(off)
    __shared__ int lds[4][112];
    int t = threadIdx.x;
    int w = t >> 6, lane = t & 63;
    int qi = blockIdx.x*4 + w;
    int b = qi >> 10;
    const float* xb = xyz + (size_t)b*3*NN;
    float qx = q[qi*3], qy = q[qi*3+1], qz = q[qi*3+2];
    float qn = qx*qx + qy*qy; qn = qn + qz*qz;
    int* l0 = lds[w];
    int* l1 = l0 + 16;
    int* l2 = l0 + 48;
    l0[lane] = 0;
    if (lane < 48) l0[64+lane] = 0;
    int c0=0, c1=0, c2=0;
    uint64_t below = (1ull << lane) - 1ull;
    for (int ch=0; ch<256; ++ch){
        int n = ch*64 + lane;
        float x = xb[n], y = xb[NN+n], z = xb[2*NN+n];
        float dn = x*x + y*y; dn = dn + z*z;
        float dot = qx*x + qy*y; dot = dot + qz*z;
        float d = -2.0f*dot + qn;
        d = d + dn;
        bool o0 = d <= r2a, o1 = d <= r2b, o2 = d <= r2c;
        uint64_t m0 = __ballot(o0), m1 = __ballot(o1), m2 = __ballot(o2);
        if (c0 < 16){
            int p = c0 + (int)__popcll(m0 & below);
            if (o0 && p < 16) l0[p] = n;
            c0 += (int)__popcll(m0); if (c0 > 16) c0 = 16;
        }
        if (c1 < 32){
            int p = c1 + (int)__popcll(m1 & below);
            if (o1 && p < 32) l1[p] = n;
            c1 += (int)__popcll(m1); if (c1 > 32) c1 = 32;
        }
        if (c2 < 64){
            int p = c2 + (int)__popcll(m2 & below);
            if (o2 && p < 64) l2[p] = n;
            c2 += (int)__popcll(m2); if (c2 > 64) c2 = 64;
        }
        if (c0>=16 && c1>=32 && c2>=64) break;
    }
    __syncthreads();
    int f0 = l0[0], f1 = l1[0], f2 = l2[0];
    if (lane >= c0 && lane < 16) l0[lane] = f0;
    if (lane >= c1 && lane < 32) l1[lane] = f1;
    if (lane >= c2)              l2[lane] = f2;
    __syncthreads();
    if (lane < 16) idx0[(size_t)qi*16 + lane] = l0[lane];
    if (lane < 32) idx1[(size_t)qi*32 + lane] = l1[lane];
    idx2[(size_t)qi*64 + lane] = l2[lane];
}

// ---------------- MAC helper ----------------
template<int UU>
__device__ __forceinline__ void fma_tile(float (&acc)[4][UU][4], float4 a4, const float* bsrow, int jbase){
#pragma unroll
    for (int uu=0; uu<UU; ++uu){
        float4 b4 = *(const float4*)(bsrow + jbase + 64*uu);
        acc[0][uu][0]+=a4.x*b4.x; acc[0][uu][1]+=a4.x*b4.y; acc[0][uu][2]+=a4.x*b4.z; acc[0][uu][3]+=a4.x*b4.w;
        acc[1][uu][0]+=a4.y*b4.x; acc[1][uu][1]+=a4.y*b4.y; acc[1][uu][2]+=a4.y*b4.z; acc[1][uu][3]+=a4.y*b4.w;
        acc[2][uu][0]+=a4.z*b4.x; acc[2][uu][1]+=a4.z*b4.y; acc[2][uu][2]+=a4.z*b4.z; acc[2][uu][3]+=a4.z*b4.w;
        acc[3][uu][0]+=a4.w*b4.x; acc[3][uu][1]+=a4.w*b4.y; acc[3][uu][2]+=a4.w*b4.z; acc[3][uu][3]+=a4.w*b4.w;
    }
}

// ---------------- unified GEMM: As [k][row] x W[OO][CC] staged in k-slabs -> acc ----------------
template<int CC, int OO>
__device__ __forceinline__ void gemm_slab(const float* __restrict__ W, int t, int i, int j,
                                          float* As, float* Bs, float (&acc)[4][OO/64][4]){
    constexpr int KS = (4096/OO) < 32 ? (4096/OO) : 32;
    constexpr int QQ = KS/4;
    constexpr int NSLOT = KS*OO/4;
    for (int k0=0; k0<CC; k0+=KS){
        __syncthreads();
#pragma unroll
        for (int it=0; it<NSLOT/256; ++it){
            int slot = t + it*256;
            int o = slot / QQ, qq = slot % QQ;
            float4 wv = *(const float4*)(W + o*CC + k0 + qq*4);
            Bs[(qq*4+0)*OO + o] = wv.x; Bs[(qq*4+1)*OO + o] = wv.y;
            Bs[(qq*4+2)*OO + o] = wv.z; Bs[(qq*4+3)*OO + o] = wv.w;
        }
        __syncthreads();
#pragma unroll 4
        for (int kk=0; kk<KS; ++kk){
            float4 a4 = *(const float4*)&As[(k0+kk)*64 + i*4];
            fma_tile<OO/64>(acc, a4, &Bs[kk*OO], j*4);
        }
    }
    __syncthreads();
}

template<int UU>
__device__ __forceinline__ void bias_add(float (&acc)[4][UU][4], const float* __restrict__ bsrc, int j){
#pragma unroll
    for (int uu=0; uu<UU; ++uu)
#pragma unroll
    for (int e=0; e<4; ++e){
        float bb = bsrc[j*4 + 64*uu + e];
#pragma unroll
        for (int rr=0; rr<4; ++rr) acc[rr][uu][e] += bb;
    }
}

template<int UU>
__device__ __forceinline__ void act_to_As(float (&acc)[4][UU][4], const float* __restrict__ bsrc,
                                          const float* __restrict__ sc, const float* __restrict__ sh,
                                          int i, int j, float* As){
#pragma unroll
    for (int uu=0; uu<UU; ++uu)
#pragma unroll
    for (int e=0; e<4; ++e){
        int c = j*4 + 64*uu + e;
        float bb = bsrc[c], scv = sc[c], shv = sh[c];
#pragma unroll
        for (int rr=0; rr<4; ++rr)
            As[c*64 + i*4+rr] = fmaxf(0.f, (acc[rr][uu][e]+bb)*scv + shv);
    }
}

template<int UU>
__device__ __forceinline__ void zstore(float (&acc)[4][UU][4], u16* __restrict__ zbuf, int m0, int i, int j){
    constexpr int OO = UU*64;
#pragma unroll
    for (int rr=0; rr<4; ++rr){
        size_t row = (size_t)(m0 + i*4 + rr);
#pragma unroll
        for (int uu=0; uu<UU; ++uu){
            ushort4 o4;
            o4.x = f2bf(acc[rr][uu][0]); o4.y = f2bf(acc[rr][uu][1]);
            o4.z = f2bf(acc[rr][uu][2]); o4.w = f2bf(acc[rr][uu][3]);
            *(ushort4*)&zbuf[row*OO + j*4 + 64*uu] = o4;
        }
    }
}

template<int OO>
__device__ __forceinline__ void zload_to_As(const u16* __restrict__ zbuf, int m0,
                                            const float* __restrict__ sc, const float* __restrict__ sh,
                                            int t, float* As){
    constexpr int CQ = OO/4;
    constexpr int ITZ = 64*CQ/256;
#pragma unroll
    for (int it=0; it<ITZ; ++it){
        int slot = t + it*256;
        int r = slot / CQ, cq = slot % CQ;
        ushort4 zv = *(const ushort4*)&zbuf[((size_t)(m0+r))*OO + cq*4];
        int c = cq*4;
        As[(c+0)*64+r] = fmaxf(0.f, bf2f(zv.x)*sc[c+0] + sh[c+0]);
        As[(c+1)*64+r] = fmaxf(0.f, bf2f(zv.y)*sc[c+1] + sh[c+1]);
        As[(c+2)*64+r] = fmaxf(0.f, bf2f(zv.z)*sc[c+2] + sh[c+2]);
        As[(c+3)*64+r] = fmaxf(0.f, bf2f(zv.w)*sc[c+3] + sh[c+3]);
    }
}

// ---------------- stats / extrema epilogue ----------------
template<int UU, int K, bool EXT>
__device__ __forceinline__ void stats_write(float (&z)[4][UU][4], int t, int m0, int blk,
    float* scr, float* __restrict__ pS, float* __restrict__ pQ,
    float* __restrict__ gmax, float* __restrict__ gmin)
{
    constexpr int O = UU*64;
    int j = t & 15;
    float s1[UU][4], s2[UU][4], mx[UU][4], mn[UU][4];
#pragma unroll
    for (int uu=0; uu<UU; ++uu)
#pragma unroll
    for (int e=0; e<4; ++e){
        float v0=z[0][uu][e], v1=z[1][uu][e], v2=z[2][uu][e], v3=z[3][uu][e];
        s1[uu][e]=(v0+v1)+(v2+v3);
        s2[uu][e]=(v0*v0+v1*v1)+(v2*v2+v3*v3);
        if (EXT){
            mx[uu][e]=fmaxf(fmaxf(v0,v1),fmaxf(v2,v3));
            mn[uu][e]=fminf(fminf(v0,v1),fminf(v2,v3));
        }
    }
#pragma unroll
    for (int uu=0; uu<UU; ++uu)
#pragma unroll
    for (int e=0; e<4; ++e){
        s1[uu][e] += __shfl_xor(s1[uu][e],16); s1[uu][e] += __shfl_xor(s1[uu][e],32);
        s2[uu][e] += __shfl_xor(s2[uu][e],16); s2[uu][e] += __shfl_xor(s2[uu][e],32);
        if (EXT){
            mx[uu][e] = fmaxf(mx[uu][e], __shfl_xor(mx[uu][e],16)); mx[uu][e] = fmaxf(mx[uu][e], __shfl_xor(mx[uu][e],32));
            mn[uu][e] = fminf(mn[uu][e], __shfl_xor(mn[uu][e],16)); mn[uu][e] = fminf(mn[uu][e], __shfl_xor(mn[uu][e],32));
        }
    }
    int wv = t >> 6;
    if ((t & 63) < 16){
#pragma unroll
        for (int uu=0; uu<UU; ++uu)
#pragma unroll
        for (int e=0; e<4; ++e){
            int c = j*4 + 64*uu + e;
            scr[0*4*O + wv*O + c] = s1[uu][e];
            scr[1*4*O + wv*O + c] = s2[uu][e];
            if (EXT){
                scr[2*4*O + wv*O + c] = mx[uu][e];
                scr[3*4*O + wv*O + c] = mn[uu][e];
            }
        }
    }
    __syncthreads();
    for (int c=t; c<O; c+=256){
        float S = ((scr[c] + scr[O+c]) + (scr[2*O+c] + scr[3*O+c]));
        float Q = ((scr[4*O+c] + scr[5*O+c]) + (scr[6*O+c] + scr[7*O+c]));
        pS[(size_t)blk*O + c] = S;
        pQ[(size_t)blk*O + c] = Q;
        if (EXT){
            constexpr int G  = 64/K;
            constexpr int WG = K/16;
#pragma unroll
            for (int g=0; g<G; ++g){
                float M1 = scr[2*4*O + (g*WG)*O + c];
                float M2 = scr[3*4*O + (g*WG)*O + c];
#pragma unroll
                for (int ww=1; ww<WG; ++ww){
                    M1 = fmaxf(M1, scr[2*4*O + (g*WG+ww)*O + c]);
                    M2 = fminf(M2, scr[3*4*O + (g*WG+ww)*O + c]);
                }
                int bs = m0/K + g;
                gmax[(size_t)bs*O + c] = M1;
                gmin[(size_t)bs*O + c] = M2;
            }
        }
    }
}

template<int K>
__device__ __forceinline__ void gather_A0(const float* __restrict__ ptsT, const float* __restrict__ q,
                                          const int* __restrict__ gidx, int m0, int t, float* As){
    int r = t >> 2, q4 = t & 3;
    int m = m0 + r;
    int idx = gidx[m];
    int bs = m / K;
    int b = bs >> 10;
    const float* base = ptsT + ((size_t)b*NN + idx)*64;
    float qx=0.f, qy=0.f, qz=0.f;
    if (q4 == 0){ qx = q[bs*3]; qy = q[bs*3+1]; qz = q[bs*3+2]; }
#pragma unroll
    for (int ii=0; ii<4; ++ii){
        int c0 = q4*16 + ii*4;
        float4 v = *(const float4*)(base + c0);
        if (q4==0 && ii==0){ v.x -= qx; v.y -= qy; v.z -= qz; }
        As[(c0+0)*64 + r] = v.x; As[(c0+1)*64 + r] = v.y;
        As[(c0+2)*64 + r] = v.z; As[(c0+3)*64 + r] = v.w;
    }
}

// ---------------- fused MLP phases ----------------
template<int PHASE, int K, int O1, int O2, int O3>
__global__ __launch_bounds__(256) void fused_mlp(
    const float* __restrict__ ptsT, const float* __restrict__ q, const int* __restrict__ gidx,
    const float* __restrict__ W1, const float* __restrict__ b1,
    const float* __restrict__ W2, const float* __restrict__ b2,
    const float* __restrict__ W3, const float* __restrict__ b3,
    const float* __restrict__ sc1, const float* __restrict__ sh1,
    const float* __restrict__ sc2, const float* __restrict__ sh2,
    float* __restrict__ pS, float* __restrict__ pQ,
    float* __restrict__ gmax, float* __restrict__ gmin,
    u16* __restrict__ zbuf)
{
    __shared__ float As[8192];   // 32 KB
    __shared__ float Bs[4096];   // 16 KB
    int t = threadIdx.x;
    int m0 = blockIdx.x * 64;
    int j = t & 15, i = t >> 4;

    if constexpr (PHASE == 1){
        gather_A0<K>(ptsT, q, gidx, m0, t, As);
        float acc1[4][O1/64][4] = {};
        gemm_slab<64,O1>(W1, t, i, j, As, Bs, acc1);
        bias_add<O1/64>(acc1, b1, j);
        if (zbuf) zstore<O1/64>(acc1, zbuf, m0, i, j);
        stats_write<O1/64,K,false>(acc1, t, m0, blockIdx.x, Bs, pS, pQ, gmax, gmin);
        return;
    }

    if constexpr (PHASE == 2){
        if (zbuf){
            zload_to_As<O1>(zbuf, m0, sc1, sh1, t, As);
        } else {
            gather_A0<K>(ptsT, q, gidx, m0, t, As);
            float acc1[4][O1/64][4] = {};
            gemm_slab<64,O1>(W1, t, i, j, As, Bs, acc1);
            act_to_As<O1/64>(acc1, b1, sc1, sh1, i, j, As);
        }
        float acc2[4][O2/64][4] = {};
        gemm_slab<O1,O2>(W2, t, i, j, As, Bs, acc2);
        bias_add<O2/64>(acc2, b2, j);
        if (zbuf) zstore<O2/64>(acc2, zbuf, m0, i, j);   // overwrites z1 rows (block-local, safe)
        stats_write<O2/64,K,false>(acc2, t, m0, blockIdx.x, Bs, pS, pQ, gmax, gmin);
        return;
    }

    if constexpr (PHASE == 3){
        gather_A0<K>(ptsT, q, gidx, m0, t, As);
        float acc1[4][O1/64][4] = {};
        gemm_slab<64,O1>(W1, t, i, j, As, Bs, acc1);
        act_to_As<O1/64>(acc1, b1, sc1, sh1, i, j, As);
        float acc2[4][O2/64][4] = {};
        gemm_slab<O1,O2>(W2, t, i, j, As, Bs, acc2);
        act_to_As<O2/64>(acc2, b2, sc2, sh2, i, j, As);
    } else {
        // PHASE 4
        zload_to_As<O2>(zbuf, m0, sc2, sh2, t, As);
    }

    float acc3[4][O3/64][4] = {};
    gemm_slab<O2,O3>(W3, t, i, j, As, Bs, acc3);
    bias_add<O3/64>(acc3, b3, j);
    stats_write<O3/64,K,true>(acc3, t, m0, blockIdx.x, Bs, pS, pQ, gmax, gmin);
}

// ---------------- finalize BN stats (fp64 accumulation) ----------------
__global__ __launch_bounds__(256) void finalize_d_kernel(const float* __restrict__ pS, const float* __restrict__ pQ,
                                      const float* __restrict__ g, const float* __restrict__ bt,
                                      float* __restrict__ sc, float* __restrict__ sh, int nb, double invM){
    __shared__ double red[512];
    int c = blockIdx.x;
    int O = gridDim.x;
    int t = threadIdx.x;
    double S=0.0, Q=0.0;
    for (int v=t; v<nb; v+=256){ S += (double)pS[(size_t)v*O + c]; Q += (double)pQ[(size_t)v*O + c]; }
    red[t]=S; red[256+t]=Q;
    __syncthreads();
    for (int s=128; s>0; s>>=1){
        if (t<s){ red[t]+=red[t+s]; red[256+t]+=red[256+t+s]; }
        __syncthreads();
    }
    if (t==0){
        double mean = red[0]*invM;
        double var  = red[256]*invM - mean*mean;
        double scale = (double)g[c] / sqrt(var + 1e-5);
        sc[c] = (float)scale;
        sh[c] = (float)((double)bt[c] - mean*scale);
    }
}

// ---------------- BN+relu on pooled extrema -> output (fp32) ----------------
__global__ void final_out_kernel(const float* __restrict__ gmax, const float* __restrict__ gmin,
                                 const float* __restrict__ sc, const float* __restrict__ sh,
                                 float* __restrict__ outp, int O, int logO, int chbase){
    int gid = blockIdx.x*256 + threadIdx.x;
    int c  = gid & (O-1);
    int bs = gid >> logO;
    int b = bs >> 10, s = bs & 1023;
    float scale = sc[c];
    float v = (scale >= 0.f) ? gmax[gid] : gmin[gid];
    float r = fmaxf(0.f, scale*v + sh[c]);
    outp[((size_t)(b*640 + chbase + c))*SS + s] = r;
}

__global__ void ws_marker_kernel(float* outp, float wsval){ if (threadIdx.x==0) outp[0] = wsval; }

template<int K, int O1, int O2, int O3>
static void run_branch(const float* ptsT, const float* q, const int* gidx,
                       float* pS, float* pQ, float* gmax, float* gmin,
                       float* sc1, float* sh1, float* sc2, float* sh2, float* sc3, float* sh3,
                       u16* z2buf, bool use_z,
                       void* const* d_in, int wbase, float* np_out, int chbase, hipStream_t stream)
{
    const int M = BB*SS*K;
    const int nb = M/64;
    auto wp = [&](int jl, int which)->const float* { return (const float*)d_in[2 + (wbase+jl)*4 + which]; };
    const double invM = 1.0 / (double)M;
    u16* zb = use_z ? z2buf : (u16*)nullptr;

    fused_mlp<1,K,O1,O2,O3><<<nb,256,0,stream>>>(ptsT,q,gidx,
        wp(0,0),wp(0,1), wp(1,0),wp(1,1), wp(2,0),wp(2,1),
        sc1,sh1, sc2,sh2, pS,pQ, gmax,gmin, zb);
    finalize_d_kernel<<<O1,256,0,stream>>>(pS,pQ, wp(0,2), wp(0,3), sc1, sh1, nb, invM);

    fused_mlp<2,K,O1,O2,O3><<<nb,256,0,stream>>>(ptsT,q,gidx,
        wp(0,0),wp(0,1), wp(1,0),wp(1,1), wp(2,0),wp(2,1),
        sc1,sh1, sc2,sh2, pS,pQ, gmax,gmin, zb);
    finalize_d_kernel<<<O2,256,0,stream>>>(pS,pQ, wp(1,2), wp(1,3), sc2, sh2, nb, invM);

    if (use_z){
        fused_mlp<4,K,O1,O2,O3><<<nb,256,0,stream>>>(ptsT,q,gidx,
            wp(0,0),wp(0,1), wp(1,0),wp(1,1), wp(2,0),wp(2,1),
            sc1,sh1, sc2,sh2, pS,pQ, gmax,gmin, z2buf);
    } else {
        fused_mlp<3,K,O1,O2,O3><<<nb,256,0,stream>>>(ptsT,q,gidx,
            wp(0,0),wp(0,1), wp(1,0),wp(1,1), wp(2,0),wp(2,1),
            sc1,sh1, sc2,sh2, pS,pQ, gmax,gmin, nullptr);
    }
    finalize_d_kernel<<<O3,256,0,stream>>>(pS,pQ, wp(2,2), wp(2,3), sc3, sh3, nb, invM);

    final_out_kernel<<<(BB*SS*O3)/256,256,0,stream>>>(gmax,gmin, sc3,sh3, np_out, O3, (O3==256?8:7), chbase);
}

extern "C" void kernel_launch(void* const* d_in, const int* in_sizes, int n_in,
                              void* d_out, int out_size, void* d_ws, size_t ws_size,
                              hipStream_t stream)
{
    const float* xyz = (const float*)d_in[0];
    const float* pts = (const float*)d_in[1];
    float* outp = (float*)d_out;

    char* wsb = (char*)d_ws;
    size_t off = 0;
    auto alloc = [&](size_t bytes) -> void* {
        off = (off + 255) & ~(size_t)255;
        void* p = wsb + off;
        off += bytes;
        return p;
    };
    int*   fps_idx = (int*)  alloc((size_t)BB*SS*4);
    float* q       = (float*)alloc((size_t)BB*SS*3*4);
    int*   idx0    = (int*)  alloc((size_t)BB*SS*16*4);
    int*   idx1    = (int*)  alloc((size_t)BB*SS*32*4);
    int*   idx2    = (int*)  alloc((size_t)BB*SS*64*4);
    float* ptsT    = (float*)alloc((size_t)BB*NN*64*4);
    float* pS      = (float*)alloc((size_t)8192*256*4);
    float* pQ      = (float*)alloc((size_t)8192*256*4);
    float* gmax    = (float*)alloc((size_t)8192*256*4);
    float* gmin    = (float*)alloc((size_t)8192*256*4);
    float* sc1     = (float*)alloc(256*4);
    float* sh1     = (float*)alloc(256*4);
    float* sc2     = (float*)alloc(256*4);
    float* sh2     = (float*)alloc(256*4);
    float* sc3     = (float*)alloc(256*4);
    float* sh3     = (float*)alloc(256*4);

    if (off > ws_size){
        ws_marker_kernel<<<1,64,0,stream>>>(outp, (float)ws_size);
        return;
    }

    u16* z2buf = (u16*)alloc((size_t)BB*SS*64*128*2);
    bool use_z = (off <= ws_size);

    build_ptsT_kernel<<<dim3(NN/64, BB), 256, 0, stream>>>(xyz, pts, ptsT);
    fps_kernel<<<BB, 1024, 0, stream>>>(xyz, fps_idx);
    gather_q_kernel<<<32, 256, 0, stream>>>(xyz, fps_idx, q, outp);

    const float r2a = (float)(0.1*0.1);
    const float r2b = (float)(0.2*0.2);
    const float r2c = (float)(0.4*0.4);
    ballquery_kernel<<<2048, 256, 0, stream>>>(xyz, q, idx0, idx1, idx2, r2a, r2b, r2c);

    float* np_out = outp + (size_t)BB*3*SS;
    run_branch<16, 64, 64,128>(ptsT, q, idx0, pS,pQ, gmax,gmin, sc1,sh1,sc2,sh2,sc3,sh3, z2buf, use_z, d_in, 0, np_out,   0, stream);
    run_branch<32,128,128,256>(ptsT, q, idx1, pS,pQ, gmax,gmin, sc1,sh1,sc2,sh2,sc3,sh3, z2buf, use_z, d_in, 3, np_out, 128, stream);
    run_branch<64,128,128,256>(ptsT, q, idx2, pS,pQ, gmax,gmin, sc1,sh1,sc2,sh2,sc3,sh3, z2buf, use_z, d_in, 6, np_out, 384, stream);

    hipError_t e = hipGetLastError();
    if (e != hipSuccess){
        ws_marker_kernel<<<1,64,0,stream>>>(outp, 1000.0f + (float)(int)e);
    }
}

// Round 3
// 3909.949 us; speedup vs baseline: 1.7846x; 1.1708x over previous
//
#include <hip/hip_runtime.h>
#include <stdint.h>

#define BB 8
#define NN 16384
#define SS 1024

typedef unsigned short u16;
static __device__ __forceinline__ float bf2f(u16 u){
    union { uint32_t u; float f; } v; v.u = ((uint32_t)u) << 16; return v.f;
}
static __device__ __forceinline__ u16 f2bf(float f){
    union { float f; uint32_t u; } v; v.f = f;
    return (u16)((v.u + 0x7FFFu + ((v.u >> 16) & 1u)) >> 16);
}

// ---------------- FPS: one block per batch, 1024 thr, 16 pts/thread ----------------
// History: R0 512x32 = 2297us; R1 4-block agent-atomic = 4808us (cross-XCD poll ~3us/iter
// + dropped asm residency -> remat reloads); R2 1024x16 = 2413us (neutral: same per-CU
// work; VGPR=56 -> AGPR shelving). R3 (this): cut issue + serial tail:
//  - inner loop 9 VALU/pt (fminf exact, no NaN possible); argmax via post-loop max3 tree
//    + first-match recovery (== lowest j == lowest n, matches jnp.argmax first-occurrence)
//  - block argmax via ONE LDS atomicMax on packed u64 (it+1)<<46 | f32bits<<14 | (16383-n):
//    monotone tag -> no resets, 1 barrier/iter; u64 max == (value, lowest-n) exactly
//  - centroid coords for first 12288 pts cached in LDS (147KB): 75% of iters avoid the
//    ~300cy L2 centroid load on the serial chain
// asm redefinition is LOAD-BEARING: prevents rematerialization of the coord loads.
#define LP 12288

__global__ __launch_bounds__(1024) void fps_kernel(const float* __restrict__ xyz,
                                                   int* __restrict__ fps_idx){
#pragma clang fp contract(off)
    __shared__ float lx[LP], ly[LP], lz[LP];
    __shared__ unsigned long long slot;
    int b = blockIdx.x;
    int t = threadIdx.x;
    const float* xb = xyz + (size_t)b*3*NN;
    float px[16], py[16], pz[16], dd[16];
#pragma unroll
    for (int j=0;j<16;++j){
        int n = t + j*1024;
        px[j] = xb[n];
        py[j] = xb[NN+n];
        pz[j] = xb[2*NN+n];
        dd[j] = 1e10f;
    }
    // opaque redefinition: compiler cannot rematerialize the loads
#pragma unroll
    for (int j=0;j<16;++j){
        asm volatile("" : "+v"(px[j]), "+v"(py[j]), "+v"(pz[j]));
    }
    // stage centroid-coord cache in LDS
    for (int idx = t; idx < LP; idx += 1024){
        lx[idx] = xb[idx];
        ly[idx] = xb[NN+idx];
        lz[idx] = xb[2*NN+idx];
    }
    if (t == 0) slot = 0ull;
    __syncthreads();

    int lane = t & 63;
    int far = 0;
    int* outp = fps_idx + b*SS;
    float cx = xb[0], cy = xb[NN], cz = xb[2*NN];
    for (int it=0; it<SS; ++it){
        if (t==0) outp[it] = far;
        // distance update: 9 VALU/pt, exact (contract off, fminf has no NaN inputs)
#pragma unroll
        for (int j=0;j<16;++j){
            float dx = px[j]-cx, dy = py[j]-cy, dz = pz[j]-cz;
            float d = dx*dx + dy*dy;
            d = d + dz*dz;
            dd[j] = fminf(dd[j], d);
        }
        // per-thread max (tree; compiler fuses to v_max3)
        float m01 = fmaxf(dd[0], dd[1]),  m23 = fmaxf(dd[2], dd[3]);
        float m45 = fmaxf(dd[4], dd[5]),  m67 = fmaxf(dd[6], dd[7]);
        float m89 = fmaxf(dd[8], dd[9]),  mab = fmaxf(dd[10], dd[11]);
        float mcd = fmaxf(dd[12], dd[13]), mef = fmaxf(dd[14], dd[15]);
        float ma = fmaxf(fmaxf(m01, m23), fmaxf(m45, m67));
        float mb = fmaxf(fmaxf(m89, mab), fmaxf(mcd, mef));
        float mx = fmaxf(ma, mb);
        // first j with dd[j]==mx (descending overwrite -> smallest j -> smallest n)
        int bj = 0;
#pragma unroll
        for (int j=15; j>=0; --j){
            if (dd[j] == mx) bj = j;
        }
        int bn = t + (bj << 10);
        // pack: [it+1:14][f32bits:32][16383-n:14]; u64 max == (value, lowest-n) argmax
        unsigned long long pk = ((unsigned long long)(unsigned)(it+1) << 46)
                              | ((unsigned long long)__float_as_uint(mx) << 14)
                              | (unsigned long long)(unsigned)(16383 - bn);
        // intra-wave reduce on packed u64
#pragma unroll
        for (int off=32; off>0; off>>=1){
            unsigned long long o = __shfl_down(pk, off);
            pk = (o > pk) ? o : pk;
        }
        if (lane == 0) atomicMax(&slot, pk);
        __syncthreads();
        unsigned long long win = slot;
        far = 16383 - (int)(win & 0x3FFFull);
        if (far < LP){
            cx = lx[far]; cy = ly[far]; cz = lz[far];
        } else {
            cx = xb[far]; cy = xb[NN+far]; cz = xb[2*NN+far];
        }
    }
}

// ---------------- gather query coords + write new_xyz output (fp32) ----------------
__global__ void gather_q_kernel(const float* __restrict__ xyz, const int* __restrict__ fps_idx,
                                float* __restrict__ q, float* __restrict__ out_xyz){
    int i = blockIdx.x*blockDim.x + threadIdx.x;
    if (i >= BB*SS) return;
    int b = i >> 10, s = i & 1023;
    int idx = fps_idx[i];
    for (int c=0;c<3;++c){
        float v = xyz[((size_t)b*3+c)*NN + idx];
        q[i*3+c] = v;
        out_xyz[((size_t)b*3+c)*SS + s] = v;
    }
}

// ---------------- build ptsT[b][n][64] ----------------
__global__ __launch_bounds__(256) void build_ptsT_kernel(const float* __restrict__ xyz, const float* __restrict__ pts,
                                                         float* __restrict__ ptsT){
    __shared__ float tile[64][65];
    int b = blockIdx.y;
    int n0 = blockIdx.x * 64;
    int t = threadIdx.x;
    int ln = t & 63, cr = t >> 6;
    for (int c = cr; c < 64; c += 4){
        float v;
        if (c < 3) v = xyz[((size_t)b*3 + c)*NN + n0 + ln];
        else       v = pts[((size_t)b*61 + (c-3))*NN + n0 + ln];
        tile[ln][c] = v;
    }
    __syncthreads();
    int lc = t & 63, nr = t >> 6;
    for (int n = nr; n < 64; n += 4){
        ptsT[((size_t)b*NN + n0 + n)*64 + lc] = tile[n][lc];
    }
}

// ---------------- ball query ----------------
__global__ __launch_bounds__(256) void ballquery_kernel(const float* __restrict__ xyz, const float* __restrict__ q,
        int* __restrict__ idx0, int* __restrict__ idx1, int* __restrict__ idx2,
        float r2a, float r2b, float r2c){
#pragma clang fp contract(off)
    __shared__ int lds[4][112];
    int t = threadIdx.x;
    int w = t >> 6, lane = t & 63;
    int qi = blockIdx.x*4 + w;
    int b = qi >> 10;
    const float* xb = xyz + (size_t)b*3*NN;
    float qx = q[qi*3], qy = q[qi*3+1], qz = q[qi*3+2];
    float qn = qx*qx + qy*qy; qn = qn + qz*qz;
    int* l0 = lds[w];
    int* l1 = l0 + 16;
    int* l2 = l0 + 48;
    l0[lane] = 0;
    if (lane < 48) l0[64+lane] = 0;
    int c0=0, c1=0, c2=0;
    uint64_t below = (1ull << lane) - 1ull;
    for (int ch=0; ch<256; ++ch){
        int n = ch*64 + lane;
        float x = xb[n], y = xb[NN+n], z = xb[2*NN+n];
        float dn = x*x + y*y; dn = dn + z*z;
        float dot = qx*x + qy*y; dot = dot + qz*z;
        float d = -2.0f*dot + qn;
        d = d + dn;
        bool o0 = d <= r2a, o1 = d <= r2b, o2 = d <= r2c;
        uint64_t m0 = __ballot(o0), m1 = __ballot(o1), m2 = __ballot(o2);
        if (c0 < 16){
            int p = c0 + (int)__popcll(m0 & below);
            if (o0 && p < 16) l0[p] = n;
            c0 += (int)__popcll(m0); if (c0 > 16) c0 = 16;
        }
        if (c1 < 32){
            int p = c1 + (int)__popcll(m1 & below);
            if (o1 && p < 32) l1[p] = n;
            c1 += (int)__popcll(m1); if (c1 > 32) c1 = 32;
        }
        if (c2 < 64){
            int p = c2 + (int)__popcll(m2 & below);
            if (o2 && p < 64) l2[p] = n;
            c2 += (int)__popcll(m2); if (c2 > 64) c2 = 64;
        }
        if (c0>=16 && c1>=32 && c2>=64) break;
    }
    __syncthreads();
    int f0 = l0[0], f1 = l1[0], f2 = l2[0];
    if (lane >= c0 && lane < 16) l0[lane] = f0;
    if (lane >= c1 && lane < 32) l1[lane] = f1;
    if (lane >= c2)              l2[lane] = f2;
    __syncthreads();
    if (lane < 16) idx0[(size_t)qi*16 + lane] = l0[lane];
    if (lane < 32) idx1[(size_t)qi*32 + lane] = l1[lane];
    idx2[(size_t)qi*64 + lane] = l2[lane];
}

// ---------------- MAC helper ----------------
template<int UU>
__device__ __forceinline__ void fma_tile(float (&acc)[4][UU][4], float4 a4, const float* bsrow, int jbase){
#pragma unroll
    for (int uu=0; uu<UU; ++uu){
        float4 b4 = *(const float4*)(bsrow + jbase + 64*uu);
        acc[0][uu][0]+=a4.x*b4.x; acc[0][uu][1]+=a4.x*b4.y; acc[0][uu][2]+=a4.x*b4.z; acc[0][uu][3]+=a4.x*b4.w;
        acc[1][uu][0]+=a4.y*b4.x; acc[1][uu][1]+=a4.y*b4.y; acc[1][uu][2]+=a4.y*b4.z; acc[1][uu][3]+=a4.y*b4.w;
        acc[2][uu][0]+=a4.z*b4.x; acc[2][uu][1]+=a4.z*b4.y; acc[2][uu][2]+=a4.z*b4.z; acc[2][uu][3]+=a4.z*b4.w;
        acc[3][uu][0]+=a4.w*b4.x; acc[3][uu][1]+=a4.w*b4.y; acc[3][uu][2]+=a4.w*b4.z; acc[3][uu][3]+=a4.w*b4.w;
    }
}

// ---------------- unified GEMM: As [k][row] x W[OO][CC] staged in k-slabs -> acc ----------------
template<int CC, int OO>
__device__ __forceinline__ void gemm_slab(const float* __restrict__ W, int t, int i, int j,
                                          float* As, float* Bs, float (&acc)[4][OO/64][4]){
    constexpr int KS = (4096/OO) < 32 ? (4096/OO) : 32;
    constexpr int QQ = KS/4;
    constexpr int NSLOT = KS*OO/4;
    for (int k0=0; k0<CC; k0+=KS){
        __syncthreads();
#pragma unroll
        for (int it=0; it<NSLOT/256; ++it){
            int slot = t + it*256;
            int o = slot / QQ, qq = slot % QQ;
            float4 wv = *(const float4*)(W + o*CC + k0 + qq*4);
            Bs[(qq*4+0)*OO + o] = wv.x; Bs[(qq*4+1)*OO + o] = wv.y;
            Bs[(qq*4+2)*OO + o] = wv.z; Bs[(qq*4+3)*OO + o] = wv.w;
        }
        __syncthreads();
#pragma unroll 4
        for (int kk=0; kk<KS; ++kk){
            float4 a4 = *(const float4*)&As[(k0+kk)*64 + i*4];
            fma_tile<OO/64>(acc, a4, &Bs[kk*OO], j*4);
        }
    }
    __syncthreads();
}

template<int UU>
__device__ __forceinline__ void bias_add(float (&acc)[4][UU][4], const float* __restrict__ bsrc, int j){
#pragma unroll
    for (int uu=0; uu<UU; ++uu)
#pragma unroll
    for (int e=0; e<4; ++e){
        float bb = bsrc[j*4 + 64*uu + e];
#pragma unroll
        for (int rr=0; rr<4; ++rr) acc[rr][uu][e] += bb;
    }
}

template<int UU>
__device__ __forceinline__ void act_to_As(float (&acc)[4][UU][4], const float* __restrict__ bsrc,
                                          const float* __restrict__ sc, const float* __restrict__ sh,
                                          int i, int j, float* As){
#pragma unroll
    for (int uu=0; uu<UU; ++uu)
#pragma unroll
    for (int e=0; e<4; ++e){
        int c = j*4 + 64*uu + e;
        float bb = bsrc[c], scv = sc[c], shv = sh[c];
#pragma unroll
        for (int rr=0; rr<4; ++rr)
            As[c*64 + i*4+rr] = fmaxf(0.f, (acc[rr][uu][e]+bb)*scv + shv);
    }
}

template<int UU>
__device__ __forceinline__ void zstore(float (&acc)[4][UU][4], u16* __restrict__ zbuf, int m0, int i, int j){
    constexpr int OO = UU*64;
#pragma unroll
    for (int rr=0; rr<4; ++rr){
        size_t row = (size_t)(m0 + i*4 + rr);
#pragma unroll
        for (int uu=0; uu<UU; ++uu){
            ushort4 o4;
            o4.x = f2bf(acc[rr][uu][0]); o4.y = f2bf(acc[rr][uu][1]);
            o4.z = f2bf(acc[rr][uu][2]); o4.w = f2bf(acc[rr][uu][3]);
            *(ushort4*)&zbuf[row*OO + j*4 + 64*uu] = o4;
        }
    }
}

template<int OO>
__device__ __forceinline__ void zload_to_As(const u16* __restrict__ zbuf, int m0,
                                            const float* __restrict__ sc, const float* __restrict__ sh,
                                            int t, float* As){
    constexpr int CQ = OO/4;
    constexpr int ITZ = 64*CQ/256;
#pragma unroll
    for (int it=0; it<ITZ; ++it){
        int slot = t + it*256;
        int r = slot / CQ, cq = slot % CQ;
        ushort4 zv = *(const ushort4*)&zbuf[((size_t)(m0+r))*OO + cq*4];
        int c = cq*4;
        As[(c+0)*64+r] = fmaxf(0.f, bf2f(zv.x)*sc[c+0] + sh[c+0]);
        As[(c+1)*64+r] = fmaxf(0.f, bf2f(zv.y)*sc[c+1] + sh[c+1]);
        As[(c+2)*64+r] = fmaxf(0.f, bf2f(zv.z)*sc[c+2] + sh[c+2]);
        As[(c+3)*64+r] = fmaxf(0.f, bf2f(zv.w)*sc[c+3] + sh[c+3]);
    }
}

// ---------------- stats / extrema epilogue ----------------
template<int UU, int K, bool EXT>
__device__ __forceinline__ void stats_write(float (&z)[4][UU][4], int t, int m0, int blk,
    float* scr, float* __restrict__ pS, float* __restrict__ pQ,
    float* __restrict__ gmax, float* __restrict__ gmin)
{
    constexpr int O = UU*64;
    int j = t & 15;
    float s1[UU][4], s2[UU][4], mx[UU][4], mn[UU][4];
#pragma unroll
    for (int uu=0; uu<UU; ++uu)
#pragma unroll
    for (int e=0; e<4; ++e){
        float v0=z[0][uu][e], v1=z[1][uu][e], v2=z[2][uu][e], v3=z[3][uu][e];
        s1[uu][e]=(v0+v1)+(v2+v3);
        s2[uu][e]=(v0*v0+v1*v1)+(v2*v2+v3*v3);
        if (EXT){
            mx[uu][e]=fmaxf(fmaxf(v0,v1),fmaxf(v2,v3));
            mn[uu][e]=fminf(fminf(v0,v1),fminf(v2,v3));
        }
    }
#pragma unroll
    for (int uu=0; uu<UU; ++uu)
#pragma unroll
    for (int e=0; e<4; ++e){
        s1[uu][e] += __shfl_xor(s1[uu][e],16); s1[uu][e] += __shfl_xor(s1[uu][e],32);
        s2[uu][e] += __shfl_xor(s2[uu][e],16); s2[uu][e] += __shfl_xor(s2[uu][e],32);
        if (EXT){
            mx[uu][e] = fmaxf(mx[uu][e], __shfl_xor(mx[uu][e],16)); mx[uu][e] = fmaxf(mx[uu][e], __shfl_xor(mx[uu][e],32));
            mn[uu][e] = fminf(mn[uu][e], __shfl_xor(mn[uu][e],16)); mn[uu][e] = fminf(mn[uu][e], __shfl_xor(mn[uu][e],32));
        }
    }
    int wv = t >> 6;
    if ((t & 63) < 16){
#pragma unroll
        for (int uu=0; uu<UU; ++uu)
#pragma unroll
        for (int e=0; e<4; ++e){
            int c = j*4 + 64*uu + e;
            scr[0*4*O + wv*O + c] = s1[uu][e];
            scr[1*4*O + wv*O + c] = s2[uu][e];
            if (EXT){
                scr[2*4*O + wv*O + c] = mx[uu][e];
                scr[3*4*O + wv*O + c] = mn[uu][e];
            }
        }
    }
    __syncthreads();
    for (int c=t; c<O; c+=256){
        float S = ((scr[c] + scr[O+c]) + (scr[2*O+c] + scr[3*O+c]));
        float Q = ((scr[4*O+c] + scr[5*O+c]) + (scr[6*O+c] + scr[7*O+c]));
        pS[(size_t)blk*O + c] = S;
        pQ[(size_t)blk*O + c] = Q;
        if (EXT){
            constexpr int G  = 64/K;
            constexpr int WG = K/16;
#pragma unroll
            for (int g=0; g<G; ++g){
                float M1 = scr[2*4*O + (g*WG)*O + c];
                float M2 = scr[3*4*O + (g*WG)*O + c];
#pragma unroll
                for (int ww=1; ww<WG; ++ww){
                    M1 = fmaxf(M1, scr[2*4*O + (g*WG+ww)*O + c]);
                    M2 = fminf(M2, scr[3*4*O + (g*WG+ww)*O + c]);
                }
                int bs = m0/K + g;
                gmax[(size_t)bs*O + c] = M1;
                gmin[(size_t)bs*O + c] = M2;
            }
        }
    }
}

template<int K>
__device__ __forceinline__ void gather_A0(const float* __restrict__ ptsT, const float* __restrict__ q,
                                          const int* __restrict__ gidx, int m0, int t, float* As){
    int r = t >> 2, q4 = t & 3;
    int m = m0 + r;
    int idx = gidx[m];
    int bs = m / K;
    int b = bs >> 10;
    const float* base = ptsT + ((size_t)b*NN + idx)*64;
    float qx=0.f, qy=0.f, qz=0.f;
    if (q4 == 0){ qx = q[bs*3]; qy = q[bs*3+1]; qz = q[bs*3+2]; }
#pragma unroll
    for (int ii=0; ii<4; ++ii){
        int c0 = q4*16 + ii*4;
        float4 v = *(const float4*)(base + c0);
        if (q4==0 && ii==0){ v.x -= qx; v.y -= qy; v.z -= qz; }
        As[(c0+0)*64 + r] = v.x; As[(c0+1)*64 + r] = v.y;
        As[(c0+2)*64 + r] = v.z; As[(c0+3)*64 + r] = v.w;
    }
}

// ---------------- fused MLP phases ----------------
template<int PHASE, int K, int O1, int O2, int O3>
__global__ __launch_bounds__(256) void fused_mlp(
    const float* __restrict__ ptsT, const float* __restrict__ q, const int* __restrict__ gidx,
    const float* __restrict__ W1, const float* __restrict__ b1,
    const float* __restrict__ W2, const float* __restrict__ b2,
    const float* __restrict__ W3, const float* __restrict__ b3,
    const float* __restrict__ sc1, const float* __restrict__ sh1,
    const float* __restrict__ sc2, const float* __restrict__ sh2,
    float* __restrict__ pS, float* __restrict__ pQ,
    float* __restrict__ gmax, float* __restrict__ gmin,
    u16* __restrict__ zbuf)
{
    __shared__ float As[8192];   // 32 KB
    __shared__ float Bs[4096];   // 16 KB
    int t = threadIdx.x;
    int m0 = blockIdx.x * 64;
    int j = t & 15, i = t >> 4;

    if constexpr (PHASE == 1){
        gather_A0<K>(ptsT, q, gidx, m0, t, As);
        float acc1[4][O1/64][4] = {};
        gemm_slab<64,O1>(W1, t, i, j, As, Bs, acc1);
        bias_add<O1/64>(acc1, b1, j);
        if (zbuf) zstore<O1/64>(acc1, zbuf, m0, i, j);
        stats_write<O1/64,K,false>(acc1, t, m0, blockIdx.x, Bs, pS, pQ, gmax, gmin);
        return;
    }

    if constexpr (PHASE == 2){
        if (zbuf){
            zload_to_As<O1>(zbuf, m0, sc1, sh1, t, As);
        } else {
            gather_A0<K>(ptsT, q, gidx, m0, t, As);
            float acc1[4][O1/64][4] = {};
            gemm_slab<64,O1>(W1, t, i, j, As, Bs, acc1);
            act_to_As<O1/64>(acc1, b1, sc1, sh1, i, j, As);
        }
        float acc2[4][O2/64][4] = {};
        gemm_slab<O1,O2>(W2, t, i, j, As, Bs, acc2);
        bias_add<O2/64>(acc2, b2, j);
        if (zbuf) zstore<O2/64>(acc2, zbuf, m0, i, j);   // overwrites z1 rows (block-local, safe)
        stats_write<O2/64,K,false>(acc2, t, m0, blockIdx.x, Bs, pS, pQ, gmax, gmin);
        return;
    }

    if constexpr (PHASE == 3){
        gather_A0<K>(ptsT, q, gidx, m0, t, As);
        float acc1[4][O1/64][4] = {};
        gemm_slab<64,O1>(W1, t, i, j, As, Bs, acc1);
        act_to_As<O1/64>(acc1, b1, sc1, sh1, i, j, As);
        float acc2[4][O2/64][4] = {};
        gemm_slab<O1,O2>(W2, t, i, j, As, Bs, acc2);
        act_to_As<O2/64>(acc2, b2, sc2, sh2, i, j, As);
    } else {
        // PHASE 4
        zload_to_As<O2>(zbuf, m0, sc2, sh2, t, As);
    }

    float acc3[4][O3/64][4] = {};
    gemm_slab<O2,O3>(W3, t, i, j, As, Bs, acc3);
    bias_add<O3/64>(acc3, b3, j);
    stats_write<O3/64,K,true>(acc3, t, m0, blockIdx.x, Bs, pS, pQ, gmax, gmin);
}

// ---------------- finalize BN stats (fp64 accumulation) ----------------
__global__ __launch_bounds__(256) void finalize_d_kernel(const float* __restrict__ pS, const float* __restrict__ pQ,
                                      const float* __restrict__ g, const float* __restrict__ bt,
                                      float* __restrict__ sc, float* __restrict__ sh, int nb, double invM){
    __shared__ double red[512];
    int c = blockIdx.x;
    int O = gridDim.x;
    int t = threadIdx.x;
    double S=0.0, Q=0.0;
    for (int v=t; v<nb; v+=256){ S += (double)pS[(size_t)v*O + c]; Q += (double)pQ[(size_t)v*O + c]; }
    red[t]=S; red[256+t]=Q;
    __syncthreads();
    for (int s=128; s>0; s>>=1){
        if (t<s){ red[t]+=red[t+s]; red[256+t]+=red[256+t+s]; }
        __syncthreads();
    }
    if (t==0){
        double mean = red[0]*invM;
        double var  = red[256]*invM - mean*mean;
        double scale = (double)g[c] / sqrt(var + 1e-5);
        sc[c] = (float)scale;
        sh[c] = (float)((double)bt[c] - mean*scale);
    }
}

// ---------------- BN+relu on pooled extrema -> output (fp32) ----------------
__global__ void final_out_kernel(const float* __restrict__ gmax, const float* __restrict__ gmin,
                                 const float* __restrict__ sc, const float* __restrict__ sh,
                                 float* __restrict__ outp, int O, int logO, int chbase){
    int gid = blockIdx.x*256 + threadIdx.x;
    int c  = gid & (O-1);
    int bs = gid >> logO;
    int b = bs >> 10, s = bs & 1023;
    float scale = sc[c];
    float v = (scale >= 0.f) ? gmax[gid] : gmin[gid];
    float r = fmaxf(0.f, scale*v + sh[c]);
    outp[((size_t)(b*640 + chbase + c))*SS + s] = r;
}

__global__ void ws_marker_kernel(float* outp, float wsval){ if (threadIdx.x==0) outp[0] = wsval; }

template<int K, int O1, int O2, int O3>
static void run_branch(const float* ptsT, const float* q, const int* gidx,
                       float* pS, float* pQ, float* gmax, float* gmin,
                       float* sc1, float* sh1, float* sc2, float* sh2, float* sc3, float* sh3,
                       u16* z2buf, bool use_z,
                       void* const* d_in, int wbase, float* np_out, int chbase, hipStream_t stream)
{
    const int M = BB*SS*K;
    const int nb = M/64;
    auto wp = [&](int jl, int which)->const float* { return (const float*)d_in[2 + (wbase+jl)*4 + which]; };
    const double invM = 1.0 / (double)M;
    u16* zb = use_z ? z2buf : (u16*)nullptr;

    fused_mlp<1,K,O1,O2,O3><<<nb,256,0,stream>>>(ptsT,q,gidx,
        wp(0,0),wp(0,1), wp(1,0),wp(1,1), wp(2,0),wp(2,1),
        sc1,sh1, sc2,sh2, pS,pQ, gmax,gmin, zb);
    finalize_d_kernel<<<O1,256,0,stream>>>(pS,pQ, wp(0,2), wp(0,3), sc1, sh1, nb, invM);

    fused_mlp<2,K,O1,O2,O3><<<nb,256,0,stream>>>(ptsT,q,gidx,
        wp(0,0),wp(0,1), wp(1,0),wp(1,1), wp(2,0),wp(2,1),
        sc1,sh1, sc2,sh2, pS,pQ, gmax,gmin, zb);
    finalize_d_kernel<<<O2,256,0,stream>>>(pS,pQ, wp(1,2), wp(1,3), sc2, sh2, nb, invM);

    if (use_z){
        fused_mlp<4,K,O1,O2,O3><<<nb,256,0,stream>>>(ptsT,q,gidx,
            wp(0,0),wp(0,1), wp(1,0),wp(1,1), wp(2,0),wp(2,1),
            sc1,sh1, sc2,sh2, pS,pQ, gmax,gmin, z2buf);
    } else {
        fused_mlp<3,K,O1,O2,O3><<<nb,256,0,stream>>>(ptsT,q,gidx,
            wp(0,0),wp(0,1), wp(1,0),wp(1,1), wp(2,0),wp(2,1),
            sc1,sh1, sc2,sh2, pS,pQ, gmax,gmin, nullptr);
    }
    finalize_d_kernel<<<O3,256,0,stream>>>(pS,pQ, wp(2,2), wp(2,3), sc3, sh3, nb, invM);

    final_out_kernel<<<(BB*SS*O3)/256,256,0,stream>>>(gmax,gmin, sc3,sh3, np_out, O3, (O3==256?8:7), chbase);
}

extern "C" void kernel_launch(void* const* d_in, const int* in_sizes, int n_in,
                              void* d_out, int out_size, void* d_ws, size_t ws_size,
                              hipStream_t stream)
{
    const float* xyz = (const float*)d_in[0];
    const float* pts = (const float*)d_in[1];
    float* outp = (float*)d_out;

    char* wsb = (char*)d_ws;
    size_t off = 0;
    auto alloc = [&](size_t bytes) -> void* {
        off = (off + 255) & ~(size_t)255;
        void* p = wsb + off;
        off += bytes;
        return p;
    };
    int*   fps_idx = (int*)  alloc((size_t)BB*SS*4);
    float* q       = (float*)alloc((size_t)BB*SS*3*4);
    int*   idx0    = (int*)  alloc((size_t)BB*SS*16*4);
    int*   idx1    = (int*)  alloc((size_t)BB*SS*32*4);
    int*   idx2    = (int*)  alloc((size_t)BB*SS*64*4);
    float* ptsT    = (float*)alloc((size_t)BB*NN*64*4);
    float* pS      = (float*)alloc((size_t)8192*256*4);
    float* pQ      = (float*)alloc((size_t)8192*256*4);
    float* gmax    = (float*)alloc((size_t)8192*256*4);
    float* gmin    = (float*)alloc((size_t)8192*256*4);
    float* sc1     = (float*)alloc(256*4);
    float* sh1     = (float*)alloc(256*4);
    float* sc2     = (float*)alloc(256*4);
    float* sh2     = (float*)alloc(256*4);
    float* sc3     = (float*)alloc(256*4);
    float* sh3     = (float*)alloc(256*4);

    if (off > ws_size){
        ws_marker_kernel<<<1,64,0,stream>>>(outp, (float)ws_size);
        return;
    }

    u16* z2buf = (u16*)alloc((size_t)BB*SS*64*128*2);
    bool use_z = (off <= ws_size);

    build_ptsT_kernel<<<dim3(NN/64, BB), 256, 0, stream>>>(xyz, pts, ptsT);
    fps_kernel<<<BB, 1024, 0, stream>>>(xyz, fps_idx);
    gather_q_kernel<<<32, 256, 0, stream>>>(xyz, fps_idx, q, outp);

    const float r2a = (float)(0.1*0.1);
    const float r2b = (float)(0.2*0.2);
    const float r2c = (float)(0.4*0.4);
    ballquery_kernel<<<2048, 256, 0, stream>>>(xyz, q, idx0, idx1, idx2, r2a, r2b, r2c);

    float* np_out = outp + (size_t)BB*3*SS;
    run_branch<16, 64, 64,128>(ptsT, q, idx0, pS,pQ, gmax,gmin, sc1,sh1,sc2,sh2,sc3,sh3, z2buf, use_z, d_in, 0, np_out,   0, stream);
    run_branch<32,128,128,256>(ptsT, q, idx1, pS,pQ, gmax,gmin, sc1,sh1,sc2,sh2,sc3,sh3, z2buf, use_z, d_in, 3, np_out, 128, stream);
    run_branch<64,128,128,256>(ptsT, q, idx2, pS,pQ, gmax,gmin, sc1,sh1,sc2,sh2,sc3,sh3, z2buf, use_z, d_in, 6, np_out, 384, stream);

    hipError_t e = hipGetLastError();
    if (e != hipSuccess){
        ws_marker_kernel<<<1,64,0,stream>>>(outp, 1000.0f + (float)(int)e);
    }
}

// Round 4
// 2798.354 us; speedup vs baseline: 2.4935x; 1.3972x over previous
//
#include <hip/hip_runtime.h>
#include <stdint.h>

#define BB 8
#define NN 16384
#define SS 1024

typedef unsigned short u16;
typedef float f32x4 __attribute__((ext_vector_type(4)));
typedef short short8v __attribute__((ext_vector_type(8)));
typedef unsigned short us4 __attribute__((ext_vector_type(4)));
typedef unsigned short us8 __attribute__((ext_vector_type(8)));

static __device__ __forceinline__ float bf2f(u16 u){
    union { uint32_t u; float f; } v; v.u = ((uint32_t)u) << 16; return v.f;
}
static __device__ __forceinline__ u16 f2bf(float f){
    union { float f; uint32_t u; } v; v.f = f;
    return (u16)((v.u + 0x7FFFu + ((v.u >> 16) & 1u)) >> 16);
}
static constexpr int cmax2(int a, int b){ return a > b ? a : b; }

// ---------------- FPS: one block per batch, 1024 thr, 16 pts/thread ----------------
// R3 winner (1767us): post-loop max tree + first-match argmax, single LDS u64 atomicMax
// with monotone tag, 147KB LDS centroid cache. Per-active-CU VALUBusy ~80% -> near
// issue-bound; cross-block split measured WORSE (R1: agent-scope poll ~3us/iter). Frozen.
// asm redefinition is LOAD-BEARING: prevents rematerialization of the coord loads.
#define LP 12288

__global__ __launch_bounds__(1024) void fps_kernel(const float* __restrict__ xyz,
                                                   int* __restrict__ fps_idx){
#pragma clang fp contract(off)
    __shared__ float lx[LP], ly[LP], lz[LP];
    __shared__ unsigned long long slot;
    int b = blockIdx.x;
    int t = threadIdx.x;
    const float* xb = xyz + (size_t)b*3*NN;
    float px[16], py[16], pz[16], dd[16];
#pragma unroll
    for (int j=0;j<16;++j){
        int n = t + j*1024;
        px[j] = xb[n];
        py[j] = xb[NN+n];
        pz[j] = xb[2*NN+n];
        dd[j] = 1e10f;
    }
#pragma unroll
    for (int j=0;j<16;++j){
        asm volatile("" : "+v"(px[j]), "+v"(py[j]), "+v"(pz[j]));
    }
    for (int idx = t; idx < LP; idx += 1024){
        lx[idx] = xb[idx];
        ly[idx] = xb[NN+idx];
        lz[idx] = xb[2*NN+idx];
    }
    if (t == 0) slot = 0ull;
    __syncthreads();

    int lane = t & 63;
    int far = 0;
    int* outp = fps_idx + b*SS;
    float cx = xb[0], cy = xb[NN], cz = xb[2*NN];
    for (int it=0; it<SS; ++it){
        if (t==0) outp[it] = far;
#pragma unroll
        for (int j=0;j<16;++j){
            float dx = px[j]-cx, dy = py[j]-cy, dz = pz[j]-cz;
            float d = dx*dx + dy*dy;
            d = d + dz*dz;
            dd[j] = fminf(dd[j], d);
        }
        float m01 = fmaxf(dd[0], dd[1]),  m23 = fmaxf(dd[2], dd[3]);
        float m45 = fmaxf(dd[4], dd[5]),  m67 = fmaxf(dd[6], dd[7]);
        float m89 = fmaxf(dd[8], dd[9]),  mab = fmaxf(dd[10], dd[11]);
        float mcd = fmaxf(dd[12], dd[13]), mef = fmaxf(dd[14], dd[15]);
        float ma = fmaxf(fmaxf(m01, m23), fmaxf(m45, m67));
        float mb = fmaxf(fmaxf(m89, mab), fmaxf(mcd, mef));
        float mx = fmaxf(ma, mb);
        int bj = 0;
#pragma unroll
        for (int j=15; j>=0; --j){
            if (dd[j] == mx) bj = j;
        }
        int bn = t + (bj << 10);
        unsigned long long pk = ((unsigned long long)(unsigned)(it+1) << 46)
                              | ((unsigned long long)__float_as_uint(mx) << 14)
                              | (unsigned long long)(unsigned)(16383 - bn);
#pragma unroll
        for (int off=32; off>0; off>>=1){
            unsigned long long o = __shfl_down(pk, off);
            pk = (o > pk) ? o : pk;
        }
        if (lane == 0) atomicMax(&slot, pk);
        __syncthreads();
        unsigned long long win = slot;
        far = 16383 - (int)(win & 0x3FFFull);
        if (far < LP){
            cx = lx[far]; cy = ly[far]; cz = lz[far];
        } else {
            cx = xb[far]; cy = xb[NN+far]; cz = xb[2*NN+far];
        }
    }
}

// ---------------- gather query coords + write new_xyz output (fp32) ----------------
__global__ void gather_q_kernel(const float* __restrict__ xyz, const int* __restrict__ fps_idx,
                                float* __restrict__ q, float* __restrict__ out_xyz){
    int i = blockIdx.x*blockDim.x + threadIdx.x;
    if (i >= BB*SS) return;
    int b = i >> 10, s = i & 1023;
    int idx = fps_idx[i];
    for (int c=0;c<3;++c){
        float v = xyz[((size_t)b*3+c)*NN + idx];
        q[i*3+c] = v;
        out_xyz[((size_t)b*3+c)*SS + s] = v;
    }
}

// ---------------- build ptsT[b][n][64] ----------------
__global__ __launch_bounds__(256) void build_ptsT_kernel(const float* __restrict__ xyz, const float* __restrict__ pts,
                                                         float* __restrict__ ptsT){
    __shared__ float tile[64][65];
    int b = blockIdx.y;
    int n0 = blockIdx.x * 64;
    int t = threadIdx.x;
    int ln = t & 63, cr = t >> 6;
    for (int c = cr; c < 64; c += 4){
        float v;
        if (c < 3) v = xyz[((size_t)b*3 + c)*NN + n0 + ln];
        else       v = pts[((size_t)b*61 + (c-3))*NN + n0 + ln];
        tile[ln][c] = v;
    }
    __syncthreads();
    int lc = t & 63, nr = t >> 6;
    for (int n = nr; n < 64; n += 4){
        ptsT[((size_t)b*NN + n0 + n)*64 + lc] = tile[n][lc];
    }
}

// ---------------- ball query ----------------
__global__ __launch_bounds__(256) void ballquery_kernel(const float* __restrict__ xyz, const float* __restrict__ q,
        int* __restrict__ idx0, int* __restrict__ idx1, int* __restrict__ idx2,
        float r2a, float r2b, float r2c){
#pragma clang fp contract(off)
    __shared__ int lds[4][112];
    int t = threadIdx.x;
    int w = t >> 6, lane = t & 63;
    int qi = blockIdx.x*4 + w;
    int b = qi >> 10;
    const float* xb = xyz + (size_t)b*3*NN;
    float qx = q[qi*3], qy = q[qi*3+1], qz = q[qi*3+2];
    float qn = qx*qx + qy*qy; qn = qn + qz*qz;
    int* l0 = lds[w];
    int* l1 = l0 + 16;
    int* l2 = l0 + 48;
    l0[lane] = 0;
    if (lane < 48) l0[64+lane] = 0;
    int c0=0, c1=0, c2=0;
    uint64_t below = (1ull << lane) - 1ull;
    for (int ch=0; ch<256; ++ch){
        int n = ch*64 + lane;
        float x = xb[n], y = xb[NN+n], z = xb[2*NN+n];
        float dn = x*x + y*y; dn = dn + z*z;
        float dot = qx*x + qy*y; dot = dot + qz*z;
        float d = -2.0f*dot + qn;
        d = d + dn;
        bool o0 = d <= r2a, o1 = d <= r2b, o2 = d <= r2c;
        uint64_t m0 = __ballot(o0), m1 = __ballot(o1), m2 = __ballot(o2);
        if (c0 < 16){
            int p = c0 + (int)__popcll(m0 & below);
            if (o0 && p < 16) l0[p] = n;
            c0 += (int)__popcll(m0); if (c0 > 16) c0 = 16;
        }
        if (c1 < 32){
            int p = c1 + (int)__popcll(m1 & below);
            if (o1 && p < 32) l1[p] = n;
            c1 += (int)__popcll(m1); if (c1 > 32) c1 = 32;
        }
        if (c2 < 64){
            int p = c2 + (int)__popcll(m2 & below);
            if (o2 && p < 64) l2[p] = n;
            c2 += (int)__popcll(m2); if (c2 > 64) c2 = 64;
        }
        if (c0>=16 && c1>=32 && c2>=64) break;
    }
    __syncthreads();
    int f0 = l0[0], f1 = l1[0], f2 = l2[0];
    if (lane >= c0 && lane < 16) l0[lane] = f0;
    if (lane >= c1 && lane < 32) l1[lane] = f1;
    if (lane >= c2)              l2[lane] = f2;
    __syncthreads();
    if (lane < 16) idx0[(size_t)qi*16 + lane] = l0[lane];
    if (lane < 32) idx1[(size_t)qi*32 + lane] = l1[lane];
    idx2[(size_t)qi*64 + lane] = l2[lane];
}

// =================== MFMA fused MLP ===================
// Layouts:
//  As (LDS): [64 rows][CC] bf16, byte = row*CC*2 + (kbyte ^ ((row&7)<<4))  (T2 swizzle)
//  Wl (LDS): [OH  o  ][CC] bf16, byte = o*CC*2   + (kbyte ^ ((o  &7)<<4))
//  A/B frags packed with IDENTICAL per-lane k-order (kg = lane>>4, 8 contiguous k):
//  MFMA k-indexing is operand-symmetric, so any consistent k-order is correct.
//  C/D (HW-verified): col = lane&15, row = (lane>>4)*4 + reg.
//  Wave tile: all 64 rows x OH/4 cols -> 4 A-frags + OH/64 B-frags per K-step.

template<int CC, int OH>
__device__ __forceinline__ void stage_W(const float* __restrict__ W, char* __restrict__ Wl, int t){
    constexpr int CH = CC/8;
    constexpr int SLOTS = OH*CH;
    for (int s = t; s < SLOTS; s += 256){
        int o = s / CH, kc = s - o*CH;
        const float* wp = W + o*CC + kc*8;
        float4 w0 = *(const float4*)(wp);
        float4 w1 = *(const float4*)(wp+4);
        us8 u;
        u[0]=f2bf(w0.x); u[1]=f2bf(w0.y); u[2]=f2bf(w0.z); u[3]=f2bf(w0.w);
        u[4]=f2bf(w1.x); u[5]=f2bf(w1.y); u[6]=f2bf(w1.z); u[7]=f2bf(w1.w);
        *(us8*)(Wl + o*(CC*2) + ((kc*16) ^ ((o&7)<<4))) = u;
    }
}

template<int K>
__device__ __forceinline__ void stage_A_gather(const float* __restrict__ ptsT, const float* __restrict__ q,
                                               const int* __restrict__ gidx, int m0, int t, char* __restrict__ As){
    int r = t >> 2, q4 = t & 3;
    int m = m0 + r;
    int idx = gidx[m];
    int bs = m / K;
    int b = bs >> 10;
    const float* base = ptsT + ((size_t)b*NN + idx)*64;
    float qx=0.f, qy=0.f, qz=0.f;
    if (q4 == 0){ qx = q[bs*3]; qy = q[bs*3+1]; qz = q[bs*3+2]; }
    int rx = (r & 7) << 4;
#pragma unroll
    for (int ii=0; ii<4; ++ii){
        int c0 = q4*16 + ii*4;
        float4 v = *(const float4*)(base + c0);
        if (q4==0 && ii==0){ v.x -= qx; v.y -= qy; v.z -= qz; }
        us4 u;
        u[0]=f2bf(v.x); u[1]=f2bf(v.y); u[2]=f2bf(v.z); u[3]=f2bf(v.w);
        *(us4*)(As + r*128 + ((c0*2) ^ rx)) = u;   // CC=64 -> 128B row stride
    }
}

template<int OP>
__device__ __forceinline__ void stage_A_z(const u16* __restrict__ zbuf, int m0,
                                          const float* __restrict__ sc, const float* __restrict__ sh,
                                          int t, char* __restrict__ As){
    constexpr int CQ = OP/4;
    for (int s = t; s < 64*CQ; s += 256){
        int r = s / CQ, cq = s - r*CQ;
        us4 zv = *(const us4*)&zbuf[((size_t)(m0+r))*OP + cq*4];
        int c = cq*4;
        us4 u;
        u[0] = f2bf(fmaxf(0.f, bf2f(zv[0])*sc[c+0] + sh[c+0]));
        u[1] = f2bf(fmaxf(0.f, bf2f(zv[1])*sc[c+1] + sh[c+1]));
        u[2] = f2bf(fmaxf(0.f, bf2f(zv[2])*sc[c+2] + sh[c+2]));
        u[3] = f2bf(fmaxf(0.f, bf2f(zv[3])*sc[c+3] + sh[c+3]));
        *(us4*)(As + r*(OP*2) + ((cq*8) ^ ((r&7)<<4))) = u;
    }
}

template<int CC, int OH>
__device__ __forceinline__ void mfma_gemm(const char* __restrict__ As, const char* __restrict__ Wl,
                                          f32x4 (&acc)[4][OH/64], int l, int w){
    constexpr int CCB = CC*2;
    int rl = l & 15, kg = l >> 4;
    const char* ap = As + rl*CCB;
    const char* wp = Wl + (w*(OH/4) + rl)*CCB;
    int axor = (rl & 7) << 4;
#pragma unroll
    for (int ks=0; ks<CC/32; ++ks){
        int karg = ((ks<<6) | (kg<<4)) ^ axor;
        short8v a0 = *(const short8v*)(ap + 0*16*CCB + karg);
        short8v a1 = *(const short8v*)(ap + 1*16*CCB + karg);
        short8v a2 = *(const short8v*)(ap + 2*16*CCB + karg);
        short8v a3 = *(const short8v*)(ap + 3*16*CCB + karg);
#pragma unroll
        for (int tc=0; tc<OH/64; ++tc){
            short8v bf = *(const short8v*)(wp + tc*16*CCB + karg);
            acc[0][tc] = __builtin_amdgcn_mfma_f32_16x16x32_bf16(a0, bf, acc[0][tc], 0,0,0);
            acc[1][tc] = __builtin_amdgcn_mfma_f32_16x16x32_bf16(a1, bf, acc[1][tc], 0,0,0);
            acc[2][tc] = __builtin_amdgcn_mfma_f32_16x16x32_bf16(a2, bf, acc[2][tc], 0,0,0);
            acc[3][tc] = __builtin_amdgcn_mfma_f32_16x16x32_bf16(a3, bf, acc[3][tc], 0,0,0);
        }
    }
}

template<int OH>
__device__ __forceinline__ void bias_mfma(f32x4 (&acc)[4][OH/64], const float* __restrict__ bsrc,
                                          int l, int w, int coff){
#pragma unroll
    for (int tc=0; tc<OH/64; ++tc){
        float bb = bsrc[coff + w*(OH/4) + tc*16 + (l&15)];
#pragma unroll
        for (int tr=0; tr<4; ++tr)
#pragma unroll
        for (int e=0; e<4; ++e) acc[tr][tc][e] += bb;
    }
}

template<int OH, int OT>
__device__ __forceinline__ void zstore_mfma(f32x4 (&acc)[4][OH/64], u16* __restrict__ zbuf,
                                            int m0, int l, int w, int coff){
#pragma unroll
    for (int tr=0; tr<4; ++tr)
#pragma unroll
    for (int e=0; e<4; ++e){
        int row = tr*16 + (l>>4)*4 + e;
#pragma unroll
        for (int tc=0; tc<OH/64; ++tc){
            int c = coff + w*(OH/4) + tc*16 + (l&15);
            zbuf[((size_t)(m0+row))*OT + c] = f2bf(acc[tr][tc][e]);
        }
    }
}

// per-col sums over all 64 rows live in ONE wave -> in-lane + shfl_xor(16/32), no LDS.
template<int OH, int OT, int K, bool EXT>
__device__ __forceinline__ void stats_mfma(f32x4 (&acc)[4][OH/64], int l, int w, int m0, int blk, int coff,
    float* __restrict__ pS, float* __restrict__ pQ,
    float* __restrict__ gmax, float* __restrict__ gmin){
#pragma unroll
    for (int tc=0; tc<OH/64; ++tc){
        float s1 = 0.f, s2 = 0.f;
        float mxr[4], mnr[4];
#pragma unroll
        for (int tr=0; tr<4; ++tr){
            float v0=acc[tr][tc][0], v1=acc[tr][tc][1], v2=acc[tr][tc][2], v3=acc[tr][tc][3];
            s1 += (v0+v1)+(v2+v3);
            s2 += (v0*v0+v1*v1)+(v2*v2+v3*v3);
            if (EXT){
                mxr[tr] = fmaxf(fmaxf(v0,v1),fmaxf(v2,v3));
                mnr[tr] = fminf(fminf(v0,v1),fminf(v2,v3));
            }
        }
        s1 += __shfl_xor(s1,16); s1 += __shfl_xor(s1,32);
        s2 += __shfl_xor(s2,16); s2 += __shfl_xor(s2,32);
        if (EXT){
#pragma unroll
            for (int tr=0; tr<4; ++tr){
                mxr[tr] = fmaxf(mxr[tr], __shfl_xor(mxr[tr],16));
                mxr[tr] = fmaxf(mxr[tr], __shfl_xor(mxr[tr],32));
                mnr[tr] = fminf(mnr[tr], __shfl_xor(mnr[tr],16));
                mnr[tr] = fminf(mnr[tr], __shfl_xor(mnr[tr],32));
            }
        }
        if (l < 16){
            int c = coff + w*(OH/4) + tc*16 + l;
            pS[(size_t)blk*OT + c] = s1;
            pQ[(size_t)blk*OT + c] = s2;
            if (EXT){
                constexpr int G = 64/K, WG = K/16;
#pragma unroll
                for (int g=0; g<G; ++g){
                    float M1 = mxr[g*WG], M2 = mnr[g*WG];
#pragma unroll
                    for (int ww=1; ww<WG; ++ww){
                        M1 = fmaxf(M1, mxr[g*WG+ww]);
                        M2 = fminf(M2, mnr[g*WG+ww]);
                    }
                    gmax[(size_t)(m0/K + g)*OT + c] = M1;
                    gmin[(size_t)(m0/K + g)*OT + c] = M2;
                }
            }
        }
    }
}

// fallback path (no zbuf): acc -> BN+relu -> As bf16 (swizzled), scattered u16 ds writes
template<int OH>
__device__ __forceinline__ void act_to_As_mfma(f32x4 (&acc)[4][OH/64], const float* __restrict__ bsrc,
    const float* __restrict__ sc, const float* __restrict__ sh, int l, int w, char* __restrict__ As){
#pragma unroll
    for (int tc=0; tc<OH/64; ++tc){
        int c = w*(OH/4) + tc*16 + (l&15);
        float bb = bsrc[c], scv = sc[c], shv = sh[c];
#pragma unroll
        for (int tr=0; tr<4; ++tr)
#pragma unroll
        for (int e=0; e<4; ++e){
            int row = tr*16 + (l>>4)*4 + e;
            float vv = fmaxf(0.f, (acc[tr][tc][e]+bb)*scv + shv);
            *(u16*)(As + row*(OH*2) + ((2*c) ^ ((row&7)<<4))) = f2bf(vv);
        }
    }
}

template<int PHASE, int K, int O1, int O2, int O3>
__global__ __launch_bounds__(256) void fused_mlp(
    const float* __restrict__ ptsT, const float* __restrict__ q, const int* __restrict__ gidx,
    const float* __restrict__ W1, const float* __restrict__ b1,
    const float* __restrict__ W2, const float* __restrict__ b2,
    const float* __restrict__ W3, const float* __restrict__ b3,
    const float* __restrict__ sc1, const float* __restrict__ sh1,
    const float* __restrict__ sc2, const float* __restrict__ sh2,
    float* __restrict__ pS, float* __restrict__ pQ,
    float* __restrict__ gmax, float* __restrict__ gmin,
    u16* __restrict__ zbuf)
{
    constexpr int OH3 = (O3 > 128) ? 128 : O3;
    constexpr int AMX = (PHASE==1) ? 64 : (PHASE==2 ? O1 : (PHASE==3 ? cmax2(O1,O2) : O2));
    constexpr int WMX = (PHASE==1) ? O1*64
                      : (PHASE==2) ? cmax2(O2*O1, O1*64)
                      : (PHASE==3) ? cmax2(cmax2(O1*64, O2*O1), OH3*O2)
                      : OH3*O2;
    __shared__ __align__(16) char smem[64*AMX*2 + WMX*2];
    char* As = smem;
    char* Wl = smem + 64*AMX*2;
    int t = threadIdx.x, l = t & 63, w = t >> 6;
    int m0 = blockIdx.x * 64;

    if constexpr (PHASE == 1){
        stage_A_gather<K>(ptsT, q, gidx, m0, t, As);
        stage_W<64,O1>(W1, Wl, t);
        __syncthreads();
        f32x4 acc[4][O1/64] = {};
        mfma_gemm<64,O1>(As, Wl, acc, l, w);
        bias_mfma<O1>(acc, b1, l, w, 0);
        if (zbuf) zstore_mfma<O1,O1>(acc, zbuf, m0, l, w, 0);
        stats_mfma<O1,O1,K,false>(acc, l, w, m0, blockIdx.x, 0, pS,pQ,gmax,gmin);
        return;
    }

    if constexpr (PHASE == 2){
        if (zbuf){
            stage_A_z<O1>(zbuf, m0, sc1, sh1, t, As);
            stage_W<O1,O2>(W2, Wl, t);
            __syncthreads();
        } else {
            stage_A_gather<K>(ptsT, q, gidx, m0, t, As);
            stage_W<64,O1>(W1, Wl, t);
            __syncthreads();
            f32x4 acc1[4][O1/64] = {};
            mfma_gemm<64,O1>(As, Wl, acc1, l, w);
            __syncthreads();
            act_to_As_mfma<O1>(acc1, b1, sc1, sh1, l, w, As);
            stage_W<O1,O2>(W2, Wl, t);
            __syncthreads();
        }
        f32x4 acc[4][O2/64] = {};
        mfma_gemm<O1,O2>(As, Wl, acc, l, w);
        bias_mfma<O2>(acc, b2, l, w, 0);
        if (zbuf) zstore_mfma<O2,O2>(acc, zbuf, m0, l, w, 0);
        stats_mfma<O2,O2,K,false>(acc, l, w, m0, blockIdx.x, 0, pS,pQ,gmax,gmin);
        return;
    }

    if constexpr (PHASE == 3){
        stage_A_gather<K>(ptsT, q, gidx, m0, t, As);
        stage_W<64,O1>(W1, Wl, t);
        __syncthreads();
        f32x4 acc1[4][O1/64] = {};
        mfma_gemm<64,O1>(As, Wl, acc1, l, w);
        __syncthreads();
        act_to_As_mfma<O1>(acc1, b1, sc1, sh1, l, w, As);
        stage_W<O1,O2>(W2, Wl, t);
        __syncthreads();
        f32x4 acc2[4][O2/64] = {};
        mfma_gemm<O1,O2>(As, Wl, acc2, l, w);
        __syncthreads();                              // all waves done reading As+Wl
        act_to_As_mfma<O2>(acc2, b2, sc2, sh2, l, w, As);
    } else {
        // PHASE 4
        stage_A_z<O2>(zbuf, m0, sc2, sh2, t, As);
    }

    constexpr int HH = O3/OH3;
#pragma unroll
    for (int h=0; h<HH; ++h){
        stage_W<O2,OH3>(W3 + (size_t)h*OH3*O2, Wl, t);
        __syncthreads();                              // covers As staging too (h==0)
        f32x4 acc[4][OH3/64] = {};
        mfma_gemm<O2,OH3>(As, Wl, acc, l, w);
        bias_mfma<OH3>(acc, b3, l, w, h*OH3);
        stats_mfma<OH3,O3,K,true>(acc, l, w, m0, blockIdx.x, h*OH3, pS,pQ,gmax,gmin);
        if (h+1 < HH) __syncthreads();                // protect Wl restage
    }
}

// ---------------- finalize BN stats (fp64 accumulation) ----------------
__global__ __launch_bounds__(256) void finalize_d_kernel(const float* __restrict__ pS, const float* __restrict__ pQ,
                                      const float* __restrict__ g, const float* __restrict__ bt,
                                      float* __restrict__ sc, float* __restrict__ sh, int nb, double invM){
    __shared__ double red[512];
    int c = blockIdx.x;
    int O = gridDim.x;
    int t = threadIdx.x;
    double S=0.0, Q=0.0;
    for (int v=t; v<nb; v+=256){ S += (double)pS[(size_t)v*O + c]; Q += (double)pQ[(size_t)v*O + c]; }
    red[t]=S; red[256+t]=Q;
    __syncthreads();
    for (int s=128; s>0; s>>=1){
        if (t<s){ red[t]+=red[t+s]; red[256+t]+=red[256+t+s]; }
        __syncthreads();
    }
    if (t==0){
        double mean = red[0]*invM;
        double var  = red[256]*invM - mean*mean;
        double scale = (double)g[c] / sqrt(var + 1e-5);
        sc[c] = (float)scale;
        sh[c] = (float)((double)bt[c] - mean*scale);
    }
}

// ---------------- BN+relu on pooled extrema -> output (fp32) ----------------
__global__ void final_out_kernel(const float* __restrict__ gmax, const float* __restrict__ gmin,
                                 const float* __restrict__ sc, const float* __restrict__ sh,
                                 float* __restrict__ outp, int O, int logO, int chbase){
    int gid = blockIdx.x*256 + threadIdx.x;
    int c  = gid & (O-1);
    int bs = gid >> logO;
    int b = bs >> 10, s = bs & 1023;
    float scale = sc[c];
    float v = (scale >= 0.f) ? gmax[gid] : gmin[gid];
    float r = fmaxf(0.f, scale*v + sh[c]);
    outp[((size_t)(b*640 + chbase + c))*SS + s] = r;
}

__global__ void ws_marker_kernel(float* outp, float wsval){ if (threadIdx.x==0) outp[0] = wsval; }

template<int K, int O1, int O2, int O3>
static void run_branch(const float* ptsT, const float* q, const int* gidx,
                       float* pS, float* pQ, float* gmax, float* gmin,
                       float* sc1, float* sh1, float* sc2, float* sh2, float* sc3, float* sh3,
                       u16* z2buf, bool use_z,
                       void* const* d_in, int wbase, float* np_out, int chbase, hipStream_t stream)
{
    const int M = BB*SS*K;
    const int nb = M/64;
    auto wp = [&](int jl, int which)->const float* { return (const float*)d_in[2 + (wbase+jl)*4 + which]; };
    const double invM = 1.0 / (double)M;
    u16* zb = use_z ? z2buf : (u16*)nullptr;

    fused_mlp<1,K,O1,O2,O3><<<nb,256,0,stream>>>(ptsT,q,gidx,
        wp(0,0),wp(0,1), wp(1,0),wp(1,1), wp(2,0),wp(2,1),
        sc1,sh1, sc2,sh2, pS,pQ, gmax,gmin, zb);
    finalize_d_kernel<<<O1,256,0,stream>>>(pS,pQ, wp(0,2), wp(0,3), sc1, sh1, nb, invM);

    fused_mlp<2,K,O1,O2,O3><<<nb,256,0,stream>>>(ptsT,q,gidx,
        wp(0,0),wp(0,1), wp(1,0),wp(1,1), wp(2,0),wp(2,1),
        sc1,sh1, sc2,sh2, pS,pQ, gmax,gmin, zb);
    finalize_d_kernel<<<O2,256,0,stream>>>(pS,pQ, wp(1,2), wp(1,3), sc2, sh2, nb, invM);

    if (use_z){
        fused_mlp<4,K,O1,O2,O3><<<nb,256,0,stream>>>(ptsT,q,gidx,
            wp(0,0),wp(0,1), wp(1,0),wp(1,1), wp(2,0),wp(2,1),
            sc1,sh1, sc2,sh2, pS,pQ, gmax,gmin, z2buf);
    } else {
        fused_mlp<3,K,O1,O2,O3><<<nb,256,0,stream>>>(ptsT,q,gidx,
            wp(0,0),wp(0,1), wp(1,0),wp(1,1), wp(2,0),wp(2,1),
            sc1,sh1, sc2,sh2, pS,pQ, gmax,gmin, nullptr);
    }
    finalize_d_kernel<<<O3,256,0,stream>>>(pS,pQ, wp(2,2), wp(2,3), sc3, sh3, nb, invM);

    final_out_kernel<<<(BB*SS*O3)/256,256,0,stream>>>(gmax,gmin, sc3,sh3, np_out, O3, (O3==256?8:7), chbase);
}

extern "C" void kernel_launch(void* const* d_in, const int* in_sizes, int n_in,
                              void* d_out, int out_size, void* d_ws, size_t ws_size,
                              hipStream_t stream)
{
    const float* xyz = (const float*)d_in[0];
    const float* pts = (const float*)d_in[1];
    float* outp = (float*)d_out;

    char* wsb = (char*)d_ws;
    size_t off = 0;
    auto alloc = [&](size_t bytes) -> void* {
        off = (off + 255) & ~(size_t)255;
        void* p = wsb + off;
        off += bytes;
        return p;
    };
    int*   fps_idx = (int*)  alloc((size_t)BB*SS*4);
    float* q       = (float*)alloc((size_t)BB*SS*3*4);
    int*   idx0    = (int*)  alloc((size_t)BB*SS*16*4);
    int*   idx1    = (int*)  alloc((size_t)BB*SS*32*4);
    int*   idx2    = (int*)  alloc((size_t)BB*SS*64*4);
    float* ptsT    = (float*)alloc((size_t)BB*NN*64*4);
    float* pS      = (float*)alloc((size_t)8192*256*4);
    float* pQ      = (float*)alloc((size_t)8192*256*4);
    float* gmax    = (float*)alloc((size_t)8192*256*4);
    float* gmin    = (float*)alloc((size_t)8192*256*4);
    float* sc1     = (float*)alloc(256*4);
    float* sh1     = (float*)alloc(256*4);
    float* sc2     = (float*)alloc(256*4);
    float* sh2     = (float*)alloc(256*4);
    float* sc3     = (float*)alloc(256*4);
    float* sh3     = (float*)alloc(256*4);

    if (off > ws_size){
        ws_marker_kernel<<<1,64,0,stream>>>(outp, (float)ws_size);
        return;
    }

    u16* z2buf = (u16*)alloc((size_t)BB*SS*64*128*2);
    bool use_z = (off <= ws_size);

    build_ptsT_kernel<<<dim3(NN/64, BB), 256, 0, stream>>>(xyz, pts, ptsT);
    fps_kernel<<<BB, 1024, 0, stream>>>(xyz, fps_idx);
    gather_q_kernel<<<32, 256, 0, stream>>>(xyz, fps_idx, q, outp);

    const float r2a = (float)(0.1*0.1);
    const float r2b = (float)(0.2*0.2);
    const float r2c = (float)(0.4*0.4);
    ballquery_kernel<<<2048, 256, 0, stream>>>(xyz, q, idx0, idx1, idx2, r2a, r2b, r2c);

    float* np_out = outp + (size_t)BB*3*SS;
    run_branch<16, 64, 64,128>(ptsT, q, idx0, pS,pQ, gmax,gmin, sc1,sh1,sc2,sh2,sc3,sh3, z2buf, use_z, d_in, 0, np_out,   0, stream);
    run_branch<32,128,128,256>(ptsT, q, idx1, pS,pQ, gmax,gmin, sc1,sh1,sc2,sh2,sc3,sh3, z2buf, use_z, d_in, 3, np_out, 128, stream);
    run_branch<64,128,128,256>(ptsT, q, idx2, pS,pQ, gmax,gmin, sc1,sh1,sc2,sh2,sc3,sh3, z2buf, use_z, d_in, 6, np_out, 384, stream);

    hipError_t e = hipGetLastError();
    if (e != hipSuccess){
        ws_marker_kernel<<<1,64,0,stream>>>(outp, 1000.0f + (float)(int)e);
    }
}

// Round 5
// 2733.986 us; speedup vs baseline: 2.5522x; 1.0235x over previous
//
#include <hip/hip_runtime.h>
#include <stdint.h>

#define BB 8
#define NN 16384
#define SS 1024

typedef unsigned short u16;
typedef float f32x4 __attribute__((ext_vector_type(4)));
typedef float f32x2 __attribute__((ext_vector_type(2)));
typedef short short8v __attribute__((ext_vector_type(8)));
typedef unsigned short us4 __attribute__((ext_vector_type(4)));
typedef unsigned short us8 __attribute__((ext_vector_type(8)));

static __device__ __forceinline__ float bf2f(u16 u){
    union { uint32_t u; float f; } v; v.u = ((uint32_t)u) << 16; return v.f;
}
static __device__ __forceinline__ u16 f2bf(float f){
    union { float f; uint32_t u; } v; v.f = f;
    return (u16)((v.u + 0x7FFFu + ((v.u >> 16) & 1u)) >> 16);
}
static constexpr int cmax2(int a, int b){ return a > b ? a : b; }

// ---------------- FPS: one block per batch, 1024 thr, 16 pts/thread ----------------
// R3: 1767us. R4 counters: VGPR=52 with 64 live array floats -> compiler targeted 8
// waves/EU (64-VGPR cap) and shelved arrays in AGPRs (accvgpr moves every access) even
// though LDS=148KB forces 1 block/CU anyway. Fix: launch_bounds(1024,4) -> 128 cap.
// Inner loop as float2 -> v_pk_sub/mul/add_f32 (exact IEEE, contract off) halves issue.
// asm redefinition is LOAD-BEARING: prevents rematerialization of the coord loads.
#define LP 12288

__global__ __launch_bounds__(1024, 4) void fps_kernel(const float* __restrict__ xyz,
                                                      int* __restrict__ fps_idx){
#pragma clang fp contract(off)
    __shared__ float lx[LP], ly[LP], lz[LP];
    __shared__ unsigned long long slot;
    int b = blockIdx.x;
    int t = threadIdx.x;
    const float* xb = xyz + (size_t)b*3*NN;
    f32x2 px[8], py[8], pz[8], dd[8];
#pragma unroll
    for (int j=0;j<8;++j){
        int n = t + (2*j)*1024;
        px[j][0] = xb[n];        px[j][1] = xb[n+1024];
        py[j][0] = xb[NN+n];     py[j][1] = xb[NN+n+1024];
        pz[j][0] = xb[2*NN+n];   pz[j][1] = xb[2*NN+n+1024];
        dd[j][0] = 1e10f;        dd[j][1] = 1e10f;
    }
#pragma unroll
    for (int j=0;j<8;++j){
        asm volatile("" : "+v"(px[j]), "+v"(py[j]), "+v"(pz[j]));
    }
    for (int idx = t; idx < LP; idx += 1024){
        lx[idx] = xb[idx];
        ly[idx] = xb[NN+idx];
        lz[idx] = xb[2*NN+idx];
    }
    if (t == 0) slot = 0ull;
    __syncthreads();

    int lane = t & 63;
    int far = 0;
    int* outp = fps_idx + b*SS;
    float cx = xb[0], cy = xb[NN], cz = xb[2*NN];
    for (int it=0; it<SS; ++it){
        if (t==0) outp[it] = far;
        f32x2 c2x; c2x[0]=cx; c2x[1]=cx;
        f32x2 c2y; c2y[0]=cy; c2y[1]=cy;
        f32x2 c2z; c2z[0]=cz; c2z[1]=cz;
#pragma unroll
        for (int j=0;j<8;++j){
            f32x2 dx = px[j]-c2x, dy = py[j]-c2y, dz = pz[j]-c2z;
            f32x2 d = dx*dx + dy*dy;     // contract off: pk_mul,pk_mul,pk_add (exact)
            d = d + dz*dz;
            dd[j][0] = fminf(dd[j][0], d[0]);
            dd[j][1] = fminf(dd[j][1], d[1]);
        }
        // per-thread max tree over 16 values (exact max, order-free)
        float m0 = fmaxf(fmaxf(dd[0][0], dd[0][1]), fmaxf(dd[1][0], dd[1][1]));
        float m1 = fmaxf(fmaxf(dd[2][0], dd[2][1]), fmaxf(dd[3][0], dd[3][1]));
        float m2 = fmaxf(fmaxf(dd[4][0], dd[4][1]), fmaxf(dd[5][0], dd[5][1]));
        float m3 = fmaxf(fmaxf(dd[6][0], dd[6][1]), fmaxf(dd[7][0], dd[7][1]));
        float mx = fmaxf(fmaxf(m0, m1), fmaxf(m2, m3));
        // first-match recovery: element idx -> n = t + idx*1024; descending scan
        int bj = 0;
#pragma unroll
        for (int idx=15; idx>=0; --idx){
            float v = (idx&1) ? dd[idx>>1][1] : dd[idx>>1][0];
            if (v == mx) bj = idx;
        }
        int bn = t + (bj << 10);
        unsigned long long pk = ((unsigned long long)(unsigned)(it+1) << 46)
                              | ((unsigned long long)__float_as_uint(mx) << 14)
                              | (unsigned long long)(unsigned)(16383 - bn);
#pragma unroll
        for (int off=32; off>0; off>>=1){
            unsigned long long o = __shfl_down(pk, off);
            pk = (o > pk) ? o : pk;
        }
        if (lane == 0) atomicMax(&slot, pk);
        __syncthreads();
        unsigned long long win = slot;
        far = 16383 - (int)(win & 0x3FFFull);
        if (far < LP){
            cx = lx[far]; cy = ly[far]; cz = lz[far];
        } else {
            cx = xb[far]; cy = xb[NN+far]; cz = xb[2*NN+far];
        }
    }
}

// ---------------- gather query coords + write new_xyz output (fp32) ----------------
__global__ void gather_q_kernel(const float* __restrict__ xyz, const int* __restrict__ fps_idx,
                                float* __restrict__ q, float* __restrict__ out_xyz){
    int i = blockIdx.x*blockDim.x + threadIdx.x;
    if (i >= BB*SS) return;
    int b = i >> 10, s = i & 1023;
    int idx = fps_idx[i];
    for (int c=0;c<3;++c){
        float v = xyz[((size_t)b*3+c)*NN + idx];
        q[i*3+c] = v;
        out_xyz[((size_t)b*3+c)*SS + s] = v;
    }
}

// ---------------- build ptsT[b][n][64] ----------------
__global__ __launch_bounds__(256) void build_ptsT_kernel(const float* __restrict__ xyz, const float* __restrict__ pts,
                                                         float* __restrict__ ptsT){
    __shared__ float tile[64][65];
    int b = blockIdx.y;
    int n0 = blockIdx.x * 64;
    int t = threadIdx.x;
    int ln = t & 63, cr = t >> 6;
    for (int c = cr; c < 64; c += 4){
        float v;
        if (c < 3) v = xyz[((size_t)b*3 + c)*NN + n0 + ln];
        else       v = pts[((size_t)b*61 + (c-3))*NN + n0 + ln];
        tile[ln][c] = v;
    }
    __syncthreads();
    int lc = t & 63, nr = t >> 6;
    for (int n = nr; n < 64; n += 4){
        ptsT[((size_t)b*NN + n0 + n)*64 + lc] = tile[n][lc];
    }
}

// ---------------- ball query ----------------
__global__ __launch_bounds__(256) void ballquery_kernel(const float* __restrict__ xyz, const float* __restrict__ q,
        int* __restrict__ idx0, int* __restrict__ idx1, int* __restrict__ idx2,
        float r2a, float r2b, float r2c){
#pragma clang fp contract(off)
    __shared__ int lds[4][112];
    int t = threadIdx.x;
    int w = t >> 6, lane = t & 63;
    int qi = blockIdx.x*4 + w;
    int b = qi >> 10;
    const float* xb = xyz + (size_t)b*3*NN;
    float qx = q[qi*3], qy = q[qi*3+1], qz = q[qi*3+2];
    float qn = qx*qx + qy*qy; qn = qn + qz*qz;
    int* l0 = lds[w];
    int* l1 = l0 + 16;
    int* l2 = l0 + 48;
    l0[lane] = 0;
    if (lane < 48) l0[64+lane] = 0;
    int c0=0, c1=0, c2=0;
    uint64_t below = (1ull << lane) - 1ull;
    for (int ch=0; ch<256; ++ch){
        int n = ch*64 + lane;
        float x = xb[n], y = xb[NN+n], z = xb[2*NN+n];
        float dn = x*x + y*y; dn = dn + z*z;
        float dot = qx*x + qy*y; dot = dot + qz*z;
        float d = -2.0f*dot + qn;
        d = d + dn;
        bool o0 = d <= r2a, o1 = d <= r2b, o2 = d <= r2c;
        uint64_t m0 = __ballot(o0), m1 = __ballot(o1), m2 = __ballot(o2);
        if (c0 < 16){
            int p = c0 + (int)__popcll(m0 & below);
            if (o0 && p < 16) l0[p] = n;
            c0 += (int)__popcll(m0); if (c0 > 16) c0 = 16;
        }
        if (c1 < 32){
            int p = c1 + (int)__popcll(m1 & below);
            if (o1 && p < 32) l1[p] = n;
            c1 += (int)__popcll(m1); if (c1 > 32) c1 = 32;
        }
        if (c2 < 64){
            int p = c2 + (int)__popcll(m2 & below);
            if (o2 && p < 64) l2[p] = n;
            c2 += (int)__popcll(m2); if (c2 > 64) c2 = 64;
        }
        if (c0>=16 && c1>=32 && c2>=64) break;
    }
    __syncthreads();
    int f0 = l0[0], f1 = l1[0], f2 = l2[0];
    if (lane >= c0 && lane < 16) l0[lane] = f0;
    if (lane >= c1 && lane < 32) l1[lane] = f1;
    if (lane >= c2)              l2[lane] = f2;
    __syncthreads();
    if (lane < 16) idx0[(size_t)qi*16 + lane] = l0[lane];
    if (lane < 32) idx1[(size_t)qi*32 + lane] = l1[lane];
    idx2[(size_t)qi*64 + lane] = l2[lane];
}

// ---------------- one-time W fp32 -> bf16 conversion (per branch: 3 layers packed) ----
__global__ void convert_w3_kernel(const float* __restrict__ A, int na,
                                  const float* __restrict__ B, int nbb,
                                  const float* __restrict__ C, int nc,
                                  u16* __restrict__ out){
    int i = blockIdx.x*256 + threadIdx.x;
    if (i < na) out[i] = f2bf(A[i]);
    else if (i < na+nbb) out[i] = f2bf(B[i-na]);
    else if (i < na+nbb+nc) out[i] = f2bf(C[i-na-nbb]);
}

// =================== MFMA fused MLP (W in registers) ===================
// R4 was LDS-issue-bound: 4 A-reads + OH/64 B-reads (~72cy ds_read_b128) vs 38cy MFMA
// per K-step, and every block re-staged + re-converted the SAME W into LDS. Now W is
// bf16 in global (converted once); each wave loads its fragments into 32-64 VGPRs
// (L2-broadcast across the 2048-8192 blocks). Inner loop: 4 A-reads + MFMAs only.
//  As (LDS): [64 rows][CC] bf16, byte = row*CC*2 + (kbyte ^ ((row&7)<<4))  (T2 swizzle)
//  A/B frags: identical per-lane k-order (k = ks*32 + (l>>4)*8 + 0..7); MFMA k-indexing
//  is operand-symmetric. C/D (HW-verified): col=lane&15, row=(lane>>4)*4+reg.

template<int CC, int OH>
__device__ __forceinline__ void load_W_frags(const u16* __restrict__ Wb,
                                             short8v (&wf)[CC/32][OH/64],
                                             int l, int w, int hoff){
    int rl = l & 15, kg = l >> 4;
#pragma unroll
    for (int ks=0; ks<CC/32; ++ks)
#pragma unroll
    for (int tc=0; tc<OH/64; ++tc){
        int col = hoff + w*(OH/4) + tc*16 + rl;
        wf[ks][tc] = *(const short8v*)(Wb + (size_t)col*CC + ks*32 + kg*8);
    }
}

template<int K>
__device__ __forceinline__ void stage_A_gather(const float* __restrict__ ptsT, const float* __restrict__ q,
                                               const int* __restrict__ gidx, int m0, int t, char* __restrict__ As){
    int r = t >> 2, q4 = t & 3;
    int m = m0 + r;
    int idx = gidx[m];
    int bs = m / K;
    int b = bs >> 10;
    const float* base = ptsT + ((size_t)b*NN + idx)*64;
    float qx=0.f, qy=0.f, qz=0.f;
    if (q4 == 0){ qx = q[bs*3]; qy = q[bs*3+1]; qz = q[bs*3+2]; }
    int rx = (r & 7) << 4;
#pragma unroll
    for (int ii=0; ii<4; ++ii){
        int c0 = q4*16 + ii*4;
        float4 v = *(const float4*)(base + c0);
        if (q4==0 && ii==0){ v.x -= qx; v.y -= qy; v.z -= qz; }
        us4 u;
        u[0]=f2bf(v.x); u[1]=f2bf(v.y); u[2]=f2bf(v.z); u[3]=f2bf(v.w);
        *(us4*)(As + r*128 + ((c0*2) ^ rx)) = u;   // CC=64 -> 128B row stride
    }
}

template<int OP>
__device__ __forceinline__ void stage_A_z(const u16* __restrict__ zbuf, int m0,
                                          const float* __restrict__ sc, const float* __restrict__ sh,
                                          int t, char* __restrict__ As){
    constexpr int CQ = OP/4;
    for (int s = t; s < 64*CQ; s += 256){
        int r = s / CQ, cq = s - r*CQ;
        us4 zv = *(const us4*)&zbuf[((size_t)(m0+r))*OP + cq*4];
        int c = cq*4;
        us4 u;
        u[0] = f2bf(fmaxf(0.f, bf2f(zv[0])*sc[c+0] + sh[c+0]));
        u[1] = f2bf(fmaxf(0.f, bf2f(zv[1])*sc[c+1] + sh[c+1]));
        u[2] = f2bf(fmaxf(0.f, bf2f(zv[2])*sc[c+2] + sh[c+2]));
        u[3] = f2bf(fmaxf(0.f, bf2f(zv[3])*sc[c+3] + sh[c+3]));
        *(us4*)(As + r*(OP*2) + ((cq*8) ^ ((r&7)<<4))) = u;
    }
}

template<int CC, int OH>
__device__ __forceinline__ void mfma_gemm_v2(const char* __restrict__ As,
                                             const short8v (&wf)[CC/32][OH/64],
                                             f32x4 (&acc)[4][OH/64], int l){
    constexpr int CCB = CC*2;
    int rl = l & 15, kg = l >> 4;
    const char* ap = As + rl*CCB;
    int axor = (rl & 7) << 4;
#pragma unroll
    for (int ks=0; ks<CC/32; ++ks){
        int karg = ((ks<<6) | (kg<<4)) ^ axor;
        short8v a0 = *(const short8v*)(ap + 0*16*CCB + karg);
        short8v a1 = *(const short8v*)(ap + 1*16*CCB + karg);
        short8v a2 = *(const short8v*)(ap + 2*16*CCB + karg);
        short8v a3 = *(const short8v*)(ap + 3*16*CCB + karg);
#pragma unroll
        for (int tc=0; tc<OH/64; ++tc){
            acc[0][tc] = __builtin_amdgcn_mfma_f32_16x16x32_bf16(a0, wf[ks][tc], acc[0][tc], 0,0,0);
            acc[1][tc] = __builtin_amdgcn_mfma_f32_16x16x32_bf16(a1, wf[ks][tc], acc[1][tc], 0,0,0);
            acc[2][tc] = __builtin_amdgcn_mfma_f32_16x16x32_bf16(a2, wf[ks][tc], acc[2][tc], 0,0,0);
            acc[3][tc] = __builtin_amdgcn_mfma_f32_16x16x32_bf16(a3, wf[ks][tc], acc[3][tc], 0,0,0);
        }
    }
}

template<int OH>
__device__ __forceinline__ void bias_mfma(f32x4 (&acc)[4][OH/64], const float* __restrict__ bsrc,
                                          int l, int w, int coff){
#pragma unroll
    for (int tc=0; tc<OH/64; ++tc){
        float bb = bsrc[coff + w*(OH/4) + tc*16 + (l&15)];
#pragma unroll
        for (int tr=0; tr<4; ++tr)
#pragma unroll
        for (int e=0; e<4; ++e) acc[tr][tc][e] += bb;
    }
}

template<int OH, int OT>
__device__ __forceinline__ void zstore_mfma(f32x4 (&acc)[4][OH/64], u16* __restrict__ zbuf,
                                            int m0, int l, int w, int coff){
#pragma unroll
    for (int tr=0; tr<4; ++tr)
#pragma unroll
    for (int e=0; e<4; ++e){
        int row = tr*16 + (l>>4)*4 + e;
#pragma unroll
        for (int tc=0; tc<OH/64; ++tc){
            int c = coff + w*(OH/4) + tc*16 + (l&15);
            zbuf[((size_t)(m0+row))*OT + c] = f2bf(acc[tr][tc][e]);
        }
    }
}

// per-col sums over all 64 rows live in ONE wave -> in-lane + shfl_xor(16/32), no LDS.
template<int OH, int OT, int K, bool EXT>
__device__ __forceinline__ void stats_mfma(f32x4 (&acc)[4][OH/64], int l, int w, int m0, int blk, int coff,
    float* __restrict__ pS, float* __restrict__ pQ,
    float* __restrict__ gmax, float* __restrict__ gmin){
#pragma unroll
    for (int tc=0; tc<OH/64; ++tc){
        float s1 = 0.f, s2 = 0.f;
        float mxr[4], mnr[4];
#pragma unroll
        for (int tr=0; tr<4; ++tr){
            float v0=acc[tr][tc][0], v1=acc[tr][tc][1], v2=acc[tr][tc][2], v3=acc[tr][tc][3];
            s1 += (v0+v1)+(v2+v3);
            s2 += (v0*v0+v1*v1)+(v2*v2+v3*v3);
            if (EXT){
                mxr[tr] = fmaxf(fmaxf(v0,v1),fmaxf(v2,v3));
                mnr[tr] = fminf(fminf(v0,v1),fminf(v2,v3));
            }
        }
        s1 += __shfl_xor(s1,16); s1 += __shfl_xor(s1,32);
        s2 += __shfl_xor(s2,16); s2 += __shfl_xor(s2,32);
        if (EXT){
#pragma unroll
            for (int tr=0; tr<4; ++tr){
                mxr[tr] = fmaxf(mxr[tr], __shfl_xor(mxr[tr],16));
                mxr[tr] = fmaxf(mxr[tr], __shfl_xor(mxr[tr],32));
                mnr[tr] = fminf(mnr[tr], __shfl_xor(mnr[tr],16));
                mnr[tr] = fminf(mnr[tr], __shfl_xor(mnr[tr],32));
            }
        }
        if (l < 16){
            int c = coff + w*(OH/4) + tc*16 + l;
            pS[(size_t)blk*OT + c] = s1;
            pQ[(size_t)blk*OT + c] = s2;
            if (EXT){
                constexpr int G = 64/K, WG = K/16;
#pragma unroll
                for (int g=0; g<G; ++g){
                    float M1 = mxr[g*WG], M2 = mnr[g*WG];
#pragma unroll
                    for (int ww=1; ww<WG; ++ww){
                        M1 = fmaxf(M1, mxr[g*WG+ww]);
                        M2 = fminf(M2, mnr[g*WG+ww]);
                    }
                    gmax[(size_t)(m0/K + g)*OT + c] = M1;
                    gmin[(size_t)(m0/K + g)*OT + c] = M2;
                }
            }
        }
    }
}

// fallback path (no zbuf): acc -> BN+relu -> As bf16 (swizzled), scattered u16 ds writes
template<int OH>
__device__ __forceinline__ void act_to_As_mfma(f32x4 (&acc)[4][OH/64], const float* __restrict__ bsrc,
    const float* __restrict__ sc, const float* __restrict__ sh, int l, int w, char* __restrict__ As){
#pragma unroll
    for (int tc=0; tc<OH/64; ++tc){
        int c = w*(OH/4) + tc*16 + (l&15);
        float bb = bsrc[c], scv = sc[c], shv = sh[c];
#pragma unroll
        for (int tr=0; tr<4; ++tr)
#pragma unroll
        for (int e=0; e<4; ++e){
            int row = tr*16 + (l>>4)*4 + e;
            float vv = fmaxf(0.f, (acc[tr][tc][e]+bb)*scv + shv);
            *(u16*)(As + row*(OH*2) + ((2*c) ^ ((row&7)<<4))) = f2bf(vv);
        }
    }
}

template<int PHASE, int K, int O1, int O2, int O3>
__global__ __launch_bounds__(256) void fused_mlp(
    const float* __restrict__ ptsT, const float* __restrict__ q, const int* __restrict__ gidx,
    const u16* __restrict__ Wb1, const float* __restrict__ b1,
    const u16* __restrict__ Wb2, const float* __restrict__ b2,
    const u16* __restrict__ Wb3, const float* __restrict__ b3,
    const float* __restrict__ sc1, const float* __restrict__ sh1,
    const float* __restrict__ sc2, const float* __restrict__ sh2,
    float* __restrict__ pS, float* __restrict__ pQ,
    float* __restrict__ gmax, float* __restrict__ gmin,
    u16* __restrict__ zbuf)
{
    constexpr int OH3 = (O3 > 128) ? 128 : O3;
    constexpr int AMX = (PHASE==1) ? 64 : (PHASE==2 ? O1 : (PHASE==3 ? cmax2(O1,O2) : O2));
    __shared__ __align__(16) char As[64*AMX*2];
    int t = threadIdx.x, l = t & 63, w = t >> 6;
    int m0 = blockIdx.x * 64;

    if constexpr (PHASE == 1){
        stage_A_gather<K>(ptsT, q, gidx, m0, t, As);
        short8v wf[2][O1/64];
        load_W_frags<64,O1>(Wb1, wf, l, w, 0);
        __syncthreads();
        f32x4 acc[4][O1/64] = {};
        mfma_gemm_v2<64,O1>(As, wf, acc, l);
        bias_mfma<O1>(acc, b1, l, w, 0);
        if (zbuf) zstore_mfma<O1,O1>(acc, zbuf, m0, l, w, 0);
        stats_mfma<O1,O1,K,false>(acc, l, w, m0, blockIdx.x, 0, pS,pQ,gmax,gmin);
        return;
    }

    if constexpr (PHASE == 2){
        if (zbuf){
            stage_A_z<O1>(zbuf, m0, sc1, sh1, t, As);
        } else {
            stage_A_gather<K>(ptsT, q, gidx, m0, t, As);
            short8v wf1[2][O1/64];
            load_W_frags<64,O1>(Wb1, wf1, l, w, 0);
            __syncthreads();
            f32x4 acc1[4][O1/64] = {};
            mfma_gemm_v2<64,O1>(As, wf1, acc1, l);
            __syncthreads();
            act_to_As_mfma<O1>(acc1, b1, sc1, sh1, l, w, As);
        }
        short8v wf[O1/32][O2/64];
        load_W_frags<O1,O2>(Wb2, wf, l, w, 0);
        __syncthreads();
        f32x4 acc[4][O2/64] = {};
        mfma_gemm_v2<O1,O2>(As, wf, acc, l);
        bias_mfma<O2>(acc, b2, l, w, 0);
        if (zbuf) zstore_mfma<O2,O2>(acc, zbuf, m0, l, w, 0);
        stats_mfma<O2,O2,K,false>(acc, l, w, m0, blockIdx.x, 0, pS,pQ,gmax,gmin);
        return;
    }

    if constexpr (PHASE == 3){
        stage_A_gather<K>(ptsT, q, gidx, m0, t, As);
        short8v wf1[2][O1/64];
        load_W_frags<64,O1>(Wb1, wf1, l, w, 0);
        __syncthreads();
        f32x4 acc1[4][O1/64] = {};
        mfma_gemm_v2<64,O1>(As, wf1, acc1, l);
        __syncthreads();
        act_to_As_mfma<O1>(acc1, b1, sc1, sh1, l, w, As);
        __syncthreads();
        short8v wf2[O1/32][O2/64];
        load_W_frags<O1,O2>(Wb2, wf2, l, w, 0);
        f32x4 acc2[4][O2/64] = {};
        mfma_gemm_v2<O1,O2>(As, wf2, acc2, l);
        __syncthreads();
        act_to_As_mfma<O2>(acc2, b2, sc2, sh2, l, w, As);
    } else {
        // PHASE 4
        stage_A_z<O2>(zbuf, m0, sc2, sh2, t, As);
    }

    __syncthreads();
    constexpr int HH = O3/OH3;
#pragma unroll
    for (int h=0; h<HH; ++h){
        short8v wf[O2/32][OH3/64];
        load_W_frags<O2,OH3>(Wb3, wf, l, w, h*OH3);
        f32x4 acc[4][OH3/64] = {};
        mfma_gemm_v2<O2,OH3>(As, wf, acc, l);
        bias_mfma<OH3>(acc, b3, l, w, h*OH3);
        stats_mfma<OH3,O3,K,true>(acc, l, w, m0, blockIdx.x, h*OH3, pS,pQ,gmax,gmin);
        // As is read-only in this loop: no barrier between halves needed
    }
}

// ---------------- finalize BN stats (fp64 accumulation) ----------------
__global__ __launch_bounds__(256) void finalize_d_kernel(const float* __restrict__ pS, const float* __restrict__ pQ,
                                      const float* __restrict__ g, const float* __restrict__ bt,
                                      float* __restrict__ sc, float* __restrict__ sh, int nb, double invM){
    __shared__ double red[512];
    int c = blockIdx.x;
    int O = gridDim.x;
    int t = threadIdx.x;
    double S=0.0, Q=0.0;
    for (int v=t; v<nb; v+=256){ S += (double)pS[(size_t)v*O + c]; Q += (double)pQ[(size_t)v*O + c]; }
    red[t]=S; red[256+t]=Q;
    __syncthreads();
    for (int s=128; s>0; s>>=1){
        if (t<s){ red[t]+=red[t+s]; red[256+t]+=red[256+t+s]; }
        __syncthreads();
    }
    if (t==0){
        double mean = red[0]*invM;
        double var  = red[256]*invM - mean*mean;
        double scale = (double)g[c] / sqrt(var + 1e-5);
        sc[c] = (float)scale;
        sh[c] = (float)((double)bt[c] - mean*scale);
    }
}

// ---------------- BN+relu on pooled extrema -> output (fp32) ----------------
__global__ void final_out_kernel(const float* __restrict__ gmax, const float* __restrict__ gmin,
                                 const float* __restrict__ sc, const float* __restrict__ sh,
                                 float* __restrict__ outp, int O, int logO, int chbase){
    int gid = blockIdx.x*256 + threadIdx.x;
    int c  = gid & (O-1);
    int bs = gid >> logO;
    int b = bs >> 10, s = bs & 1023;
    float scale = sc[c];
    float v = (scale >= 0.f) ? gmax[gid] : gmin[gid];
    float r = fmaxf(0.f, scale*v + sh[c]);
    outp[((size_t)(b*640 + chbase + c))*SS + s] = r;
}

__global__ void ws_marker_kernel(float* outp, float wsval){ if (threadIdx.x==0) outp[0] = wsval; }

template<int K, int O1, int O2, int O3>
static void run_branch(const float* ptsT, const float* q, const int* gidx,
                       float* pS, float* pQ, float* gmax, float* gmin,
                       float* sc1, float* sh1, float* sc2, float* sh2, float* sc3, float* sh3,
                       u16* z2buf, bool use_z, const u16* wb,
                       void* const* d_in, int wbase, float* np_out, int chbase, hipStream_t stream)
{
    const int M = BB*SS*K;
    const int nb = M/64;
    auto wp = [&](int jl, int which)->const float* { return (const float*)d_in[2 + (wbase+jl)*4 + which]; };
    const double invM = 1.0 / (double)M;
    u16* zb = use_z ? z2buf : (u16*)nullptr;
    const u16* Wb1 = wb;
    const u16* Wb2 = wb + (size_t)O1*64;
    const u16* Wb3 = wb + (size_t)O1*64 + (size_t)O2*O1;

    fused_mlp<1,K,O1,O2,O3><<<nb,256,0,stream>>>(ptsT,q,gidx,
        Wb1,wp(0,1), Wb2,wp(1,1), Wb3,wp(2,1),
        sc1,sh1, sc2,sh2, pS,pQ, gmax,gmin, zb);
    finalize_d_kernel<<<O1,256,0,stream>>>(pS,pQ, wp(0,2), wp(0,3), sc1, sh1, nb, invM);

    fused_mlp<2,K,O1,O2,O3><<<nb,256,0,stream>>>(ptsT,q,gidx,
        Wb1,wp(0,1), Wb2,wp(1,1), Wb3,wp(2,1),
        sc1,sh1, sc2,sh2, pS,pQ, gmax,gmin, zb);
    finalize_d_kernel<<<O2,256,0,stream>>>(pS,pQ, wp(1,2), wp(1,3), sc2, sh2, nb, invM);

    if (use_z){
        fused_mlp<4,K,O1,O2,O3><<<nb,256,0,stream>>>(ptsT,q,gidx,
            Wb1,wp(0,1), Wb2,wp(1,1), Wb3,wp(2,1),
            sc1,sh1, sc2,sh2, pS,pQ, gmax,gmin, z2buf);
    } else {
        fused_mlp<3,K,O1,O2,O3><<<nb,256,0,stream>>>(ptsT,q,gidx,
            Wb1,wp(0,1), Wb2,wp(1,1), Wb3,wp(2,1),
            sc1,sh1, sc2,sh2, pS,pQ, gmax,gmin, nullptr);
    }
    finalize_d_kernel<<<O3,256,0,stream>>>(pS,pQ, wp(2,2), wp(2,3), sc3, sh3, nb, invM);

    final_out_kernel<<<(BB*SS*O3)/256,256,0,stream>>>(gmax,gmin, sc3,sh3, np_out, O3, (O3==256?8:7), chbase);
}

extern "C" void kernel_launch(void* const* d_in, const int* in_sizes, int n_in,
                              void* d_out, int out_size, void* d_ws, size_t ws_size,
                              hipStream_t stream)
{
    const float* xyz = (const float*)d_in[0];
    const float* pts = (const float*)d_in[1];
    float* outp = (float*)d_out;

    char* wsb = (char*)d_ws;
    size_t off = 0;
    auto alloc = [&](size_t bytes) -> void* {
        off = (off + 255) & ~(size_t)255;
        void* p = wsb + off;
        off += bytes;
        return p;
    };
    int*   fps_idx = (int*)  alloc((size_t)BB*SS*4);
    float* q       = (float*)alloc((size_t)BB*SS*3*4);
    int*   idx0    = (int*)  alloc((size_t)BB*SS*16*4);
    int*   idx1    = (int*)  alloc((size_t)BB*SS*32*4);
    int*   idx2    = (int*)  alloc((size_t)BB*SS*64*4);
    float* ptsT    = (float*)alloc((size_t)BB*NN*64*4);
    float* pS      = (float*)alloc((size_t)8192*256*4);
    float* pQ      = (float*)alloc((size_t)8192*256*4);
    float* gmax    = (float*)alloc((size_t)8192*256*4);
    float* gmin    = (float*)alloc((size_t)8192*256*4);
    float* sc1     = (float*)alloc(256*4);
    float* sh1     = (float*)alloc(256*4);
    float* sc2     = (float*)alloc(256*4);
    float* sh2     = (float*)alloc(256*4);
    float* sc3     = (float*)alloc(256*4);
    float* sh3     = (float*)alloc(256*4);
    u16*   wbf0    = (u16*)  alloc((size_t)16384*2);
    u16*   wbf1    = (u16*)  alloc((size_t)57344*2);
    u16*   wbf2    = (u16*)  alloc((size_t)57344*2);

    if (off > ws_size){
        ws_marker_kernel<<<1,64,0,stream>>>(outp, (float)ws_size);
        return;
    }

    u16* z2buf = (u16*)alloc((size_t)BB*SS*64*128*2);
    bool use_z = (off <= ws_size);

    auto wptr = [&](int layer)->const float* { return (const float*)d_in[2 + layer*4 + 0]; };
    convert_w3_kernel<<<64, 256, 0, stream>>>(wptr(0), 4096, wptr(1), 4096, wptr(2), 8192, wbf0);
    convert_w3_kernel<<<224, 256, 0, stream>>>(wptr(3), 8192, wptr(4), 16384, wptr(5), 32768, wbf1);
    convert_w3_kernel<<<224, 256, 0, stream>>>(wptr(6), 8192, wptr(7), 16384, wptr(8), 32768, wbf2);

    build_ptsT_kernel<<<dim3(NN/64, BB), 256, 0, stream>>>(xyz, pts, ptsT);
    fps_kernel<<<BB, 1024, 0, stream>>>(xyz, fps_idx);
    gather_q_kernel<<<32, 256, 0, stream>>>(xyz, fps_idx, q, outp);

    const float r2a = (float)(0.1*0.1);
    const float r2b = (float)(0.2*0.2);
    const float r2c = (float)(0.4*0.4);
    ballquery_kernel<<<2048, 256, 0, stream>>>(xyz, q, idx0, idx1, idx2, r2a, r2b, r2c);

    float* np_out = outp + (size_t)BB*3*SS;
    run_branch<16, 64, 64,128>(ptsT, q, idx0, pS,pQ, gmax,gmin, sc1,sh1,sc2,sh2,sc3,sh3, z2buf, use_z, wbf0, d_in, 0, np_out,   0, stream);
    run_branch<32,128,128,256>(ptsT, q, idx1, pS,pQ, gmax,gmin, sc1,sh1,sc2,sh2,sc3,sh3, z2buf, use_z, wbf1, d_in, 3, np_out, 128, stream);
    run_branch<64,128,128,256>(ptsT, q, idx2, pS,pQ, gmax,gmin, sc1,sh1,sc2,sh2,sc3,sh3, z2buf, use_z, wbf2, d_in, 6, np_out, 384, stream);

    hipError_t e = hipGetLastError();
    if (e != hipSuccess){
        ws_marker_kernel<<<1,64,0,stream>>>(outp, 1000.0f + (float)(int)e);
    }
}